// Round 4
// baseline (424.706 us; speedup 1.0000x reference)
//
#include <hip/hip_runtime.h>
#include <hip/hip_bf16.h>

typedef __hip_bfloat16 bf16;
typedef __bf16 bfx8 __attribute__((ext_vector_type(8)));
typedef float f32x4 __attribute__((ext_vector_type(4)));

typedef __attribute__((address_space(3))) void lds_void_t;
typedef const __attribute__((address_space(1))) void gbl_void_t;

// ---------------------------------------------------------------------------
// Fused prep: HT[e][n] = bf16(H[n][e]); optional Hb[n][e] = bf16(H[n][e]);
// de[e] += colsum; dvr[n] += row.w
__global__ void prep_kernel(const float* __restrict__ H, const float* __restrict__ w,
                            bf16* __restrict__ HT, bf16* __restrict__ Hb,
                            float* __restrict__ de, float* __restrict__ dvr, int N, int E) {
    __shared__ bf16 tile[64][65];
    __shared__ float cred[4][64];
    __shared__ float rred[4][64];
    int eb = blockIdx.x * 64, nb = blockIdx.y * 64;
    int tid = threadIdx.x;
    int c = tid & 63, g = tid >> 6;

    float cs = 0.f;
#pragma unroll
    for (int k = 0; k < 16; k++) {
        int r = g + (k << 2);
        float v = H[(size_t)(nb + r) * E + eb + c];
        bf16 bv = __float2bfloat16(v);
        tile[r][c] = bv;
        if (Hb) Hb[(size_t)(nb + r) * E + eb + c] = bv;  // row-major copy (coalesced in e)
        cs += v;
    }
    cred[g][c] = cs;
    __syncthreads();
    if (g == 0) {
        float s = cred[0][c] + cred[1][c] + cred[2][c] + cred[3][c];
        atomicAdd(&de[eb + c], s);
    }
    float rs = 0.f;
#pragma unroll
    for (int k = 0; k < 16; k++) {
        int cc = g + (k << 2);
        rs += __bfloat162float(tile[c][cc]) * w[eb + cc];
    }
    rred[g][c] = rs;
    __syncthreads();
    if (g == 1) {
        float s = rred[0][c] + rred[1][c] + rred[2][c] + rred[3][c];
        atomicAdd(&dvr[nb + c], s);
    }
#pragma unroll
    for (int k = 0; k < 16; k++) {
        int r = g + (k << 2);
        HT[(size_t)(eb + r) * N + nb + c] = tile[c][r];  // transposed (coalesced in n)
    }
}

// ---------------------------------------------------------------------------
// K3: xs_t[z*256+o][n] = (sum_d W[o][d]*x[z][n][d] + bias[o]) * rsqrt(dvr[n]+eps)
// 256x64 tile (o x n), grid (64, 8) = 512 blocks (2/CU); x read exactly once.
__global__ __launch_bounds__(256) void gemm_k3(
    const float* __restrict__ W, const float* __restrict__ x,
    const float* __restrict__ bias, const float* __restrict__ dvr,
    bf16* __restrict__ xs_t) {
    __shared__ __align__(16) bf16 As[256 * 40];  // W: 256 o x 32 k (+8 pad)
    __shared__ __align__(16) bf16 Bs[64 * 40];   // x: 64 n x 32 k

    const int bx = blockIdx.x, z = blockIdx.y;
    const int tid = threadIdx.x;
    const int wave = tid >> 6, lane = tid & 63;
    const int wr = wave * 64;  // o-rows of this wave
    const int lcol = lane & 15, quad = lane >> 4;
    const float* xp = x + (size_t)z * 1048576 + (size_t)bx * 64 * 256;

    f32x4 acc[4][4];
#pragma unroll
    for (int i = 0; i < 4; i++)
#pragma unroll
        for (int j = 0; j < 4; j++) acc[i][j] = (f32x4){0.f, 0.f, 0.f, 0.f};

    for (int k0 = 0; k0 < 256; k0 += 32) {
#pragma unroll
        for (int c = 0; c < 4; c++) {  // A (W): 8192 elems, 4 chunks/thread
            int ch = tid + c * 256;
            int r = ch >> 2, kc = (ch & 3) << 3;
            f32x4 p0 = *(const f32x4*)&W[(size_t)r * 256 + k0 + kc];
            f32x4 p1 = *(const f32x4*)&W[(size_t)r * 256 + k0 + kc + 4];
            bfx8 va;
#pragma unroll
            for (int t = 0; t < 4; t++) { va[t] = (__bf16)p0[t]; va[4 + t] = (__bf16)p1[t]; }
            *(bfx8*)&As[r * 40 + kc] = va;
        }
        {  // B (x): 2048 elems, 1 chunk/thread
            int r = tid >> 2, kc = (tid & 3) << 3;
            f32x4 q0 = *(const f32x4*)&xp[(size_t)r * 256 + k0 + kc];
            f32x4 q1 = *(const f32x4*)&xp[(size_t)r * 256 + k0 + kc + 4];
            bfx8 vb;
#pragma unroll
            for (int t = 0; t < 4; t++) { vb[t] = (__bf16)q0[t]; vb[4 + t] = (__bf16)q1[t]; }
            *(bfx8*)&Bs[r * 40 + kc] = vb;
        }
        __syncthreads();

        bfx8 af[4], bfr[4];
#pragma unroll
        for (int i = 0; i < 4; i++)
            af[i] = *(const bfx8*)&As[(wr + i * 16 + lcol) * 40 + quad * 8];
#pragma unroll
        for (int j = 0; j < 4; j++)
            bfr[j] = *(const bfx8*)&Bs[(j * 16 + lcol) * 40 + quad * 8];
#pragma unroll
        for (int i = 0; i < 4; i++)
#pragma unroll
            for (int j = 0; j < 4; j++)
                acc[i][j] = __builtin_amdgcn_mfma_f32_16x16x32_bf16(af[i], bfr[j], acc[i][j], 0, 0, 0);
        __syncthreads();
    }

#pragma unroll
    for (int j = 0; j < 4; j++) {
        int n = bx * 64 + j * 16 + lcol;
        float dn = rsqrtf(dvr[n] + 1e-8f);
#pragma unroll
        for (int i = 0; i < 4; i++) {
#pragma unroll
            for (int r = 0; r < 4; r++) {
                int o = wr + i * 16 + quad * 4 + r;
                float v = (acc[i][j][r] + bias[o]) * dn;
                xs_t[(size_t)(z * 256 + o) * 4096 + n] = __float2bfloat16(v);
            }
        }
    }
}

// ---------------------------------------------------------------------------
// 256x256 8-phase GEMM (T1+T2+T3+T4+T5), BK=64, 8 waves (2Mx4N), 512 thr.
// B^T form. Split-K via blockIdx.z. LDS 128 KiB, XOR swizzle both-sides
// (rule 21). Stage rotation per K-tile u (ROUND-2 schedule, best measured):
// P1:A0(u+1) P2:A1(u+1) (opposite buf) P3:B0(u+2) P4:B1(u+2) (same buf, B
// reads retired at P2-end barrier). vmcnt(4) once per tile at P4 -> A(u+1)
// and B(u+1) landed, B(u+2)'s 4 loads stay in flight. Never vmcnt(0) in loop.
//
// FUSED split-K reduction (flags != nullptr): every block writes its bf16
// partial to P + z*sStride, __threadfence (release), atomicAdd on the tile
// flag; the block drawing old==NZ-1 fences (acquire) and combines all NZ
// partials vectorized: MODE 4 -> t_t[c][e] = sum * (ew[e]/(de[e]+eps));
// MODE 5 -> out[b][n][o] = rsqrt(dvr[n]+eps) * sum  (f32, final output).
// Order-independent, spin-free; flags zeroed by host-side memset per launch.

#define STG_A(cb, h, u) do { \
    __builtin_amdgcn_global_load_lds((gbl_void_t*)(ga##h##0 + (size_t)(u) * 64), \
        (lds_void_t*)&SM[(cb) * 16384 + (h) * 8192 + dOff], 16, 0, 0); \
    __builtin_amdgcn_global_load_lds((gbl_void_t*)(ga##h##1 + (size_t)(u) * 64), \
        (lds_void_t*)&SM[(cb) * 16384 + (h) * 8192 + 4096 + dOff], 16, 0, 0); \
} while (0)

#define STG_B(cb, h, u) do { \
    __builtin_amdgcn_global_load_lds((gbl_void_t*)(gb##h##0 + (size_t)(u) * 64), \
        (lds_void_t*)&SM[32768 + (cb) * 16384 + (h) * 8192 + dOff], 16, 0, 0); \
    __builtin_amdgcn_global_load_lds((gbl_void_t*)(gb##h##1 + (size_t)(u) * 64), \
        (lds_void_t*)&SM[32768 + (cb) * 16384 + (h) * 8192 + 4096 + dOff], 16, 0, 0); \
} while (0)

#define LDA_(cb, qi, i, kk) \
    (*(const bfx8*)&SM[(cb) * 16384 + aBase + ((qi) * 64 + (i) * 16) * 64 + ra##kk])
#define LDB_(cb, j, kk) \
    (*(const bfx8*)&SM[32768 + (cb) * 16384 + bjb[j] + ra##kk])

#define PH_MFMA(I0, J0) do { \
    __builtin_amdgcn_s_setprio(1); \
    _Pragma("unroll") \
    for (int i_ = 0; i_ < 4; i_++) { \
        _Pragma("unroll") \
        for (int jj_ = 0; jj_ < 2; jj_++) { \
            acc[(I0) + i_][(J0) + jj_] = __builtin_amdgcn_mfma_f32_16x16x32_bf16( \
                af[i_][0], bf[(J0) + jj_][0], acc[(I0) + i_][(J0) + jj_], 0, 0, 0); \
            acc[(I0) + i_][(J0) + jj_] = __builtin_amdgcn_mfma_f32_16x16x32_bf16( \
                af[i_][1], bf[(J0) + jj_][1], acc[(I0) + i_][(J0) + jj_], 0, 0, 0); \
        } \
    } \
    __builtin_amdgcn_s_setprio(0); \
} while (0)

#define KTILE(cb, uA, uB) do { \
    /* P1: A-quad0 + B j01 reads, stage A0(next, buf cb^1) */ \
    _Pragma("unroll") \
    for (int i_ = 0; i_ < 4; i_++) { af[i_][0] = LDA_(cb, 0, i_, 0); af[i_][1] = LDA_(cb, 0, i_, 1); } \
    _Pragma("unroll") \
    for (int j_ = 0; j_ < 2; j_++) { bf[j_][0] = LDB_(cb, j_, 0); bf[j_][1] = LDB_(cb, j_, 1); } \
    STG_A((cb) ^ 1, 0, uA); \
    __builtin_amdgcn_s_barrier(); \
    PH_MFMA(0, 0); \
    __builtin_amdgcn_s_barrier(); \
    /* P2: B j23 reads, stage A1(next) */ \
    _Pragma("unroll") \
    for (int j_ = 0; j_ < 2; j_++) { bf[2 + j_][0] = LDB_(cb, 2 + j_, 0); bf[2 + j_][1] = LDB_(cb, 2 + j_, 1); } \
    STG_A((cb) ^ 1, 1, uA); \
    __builtin_amdgcn_s_barrier(); \
    PH_MFMA(0, 2); \
    __builtin_amdgcn_s_barrier(); \
    /* P3: A-quad1 reads, stage B0(u+2) into current buf (B reads retired) */ \
    _Pragma("unroll") \
    for (int i_ = 0; i_ < 4; i_++) { af[i_][0] = LDA_(cb, 1, i_, 0); af[i_][1] = LDA_(cb, 1, i_, 1); } \
    STG_B(cb, 0, uB); \
    __builtin_amdgcn_s_barrier(); \
    PH_MFMA(4, 2); \
    __builtin_amdgcn_s_barrier(); \
    /* P4: stage B1(u+2); counted vmcnt once per K-tile */ \
    STG_B(cb, 1, uB); \
    __builtin_amdgcn_s_barrier(); \
    PH_MFMA(4, 0); \
    asm volatile("s_waitcnt vmcnt(4)" ::: "memory"); \
    __builtin_amdgcn_s_barrier(); \
} while (0)

template <int MODE>
__global__ __launch_bounds__(512, 2) void gemm8ph(
    const bf16* __restrict__ A, const bf16* __restrict__ Bt, int Kst, int kLen,
    bf16* __restrict__ P, long long sStride, int ldc,
    int* __restrict__ flags, const float* __restrict__ sv1, const float* __restrict__ sv2,
    bf16* __restrict__ ttOut, float* __restrict__ outF) {
    __shared__ __align__(16) bf16 SM[65536];  // 128 KiB

    // XCD-bijective swizzle (nwg % 8 == 0 for both launch shapes)
    const int nx = gridDim.x, ny = gridDim.y;
    const int nwg = nx * ny * gridDim.z;
    const int lin = (blockIdx.z * ny + blockIdx.y) * nx + blockIdx.x;
    const int cpx = nwg >> 3;
    const int swz = (lin & 7) * cpx + (lin >> 3);
    const int bx = swz % nx;
    const int t1 = swz / nx;
    const int by = t1 % ny;
    const int bz = t1 / ny;
    const int kBase = bz * kLen;
    const int NT = kLen >> 6;
    const int NZ = (MODE == 4) ? 4 : 2;

    const int tid = threadIdx.x;
    const int lane = tid & 63, wave = tid >> 6;
    const int lcol = lane & 15, quad = lane >> 4;
    const int wr = (wave >> 2) * 128, wc = (wave & 3) * 64;
    const int aBase = (wave >> 2) * 8192;  // A half this wave reads
    const int xr = lcol & 7;               // read-side xor (== rowInHalf & 7)

    const int rowBase = by * 256, colBase = bx * 256;

    // fragment read offsets (bf16 elems): row*64 + (slot^xr)*8
    const int ra0 = lcol * 64 + ((quad ^ xr) << 3);
    const int ra1 = lcol * 64 + (((4 + quad) ^ xr) << 3);
    int bjb[4];
#pragma unroll
    for (int j = 0; j < 4; j++) {
        int rg = wc + j * 16;
        bjb[j] = ((rg >> 7) * 8192) + ((rg & 127) * 64);
    }

    // staging: thread t -> (row = t/8 + l*64, 16B-slot = t&7) per half-tile;
    // global source pre-swizzled: element col = (slot ^ (row&7))*8
    const int srow = tid >> 3, slot = tid & 7;
    const int r0 = srow, r1 = srow + 64;
    const int sx0 = (slot ^ (r0 & 7)) << 3;
    const int sx1 = (slot ^ (r1 & 7)) << 3;
    const bf16* ga00 = A + (size_t)(rowBase + r0) * Kst + kBase + sx0;
    const bf16* ga01 = A + (size_t)(rowBase + r1) * Kst + kBase + sx1;
    const bf16* ga10 = A + (size_t)(rowBase + 128 + r0) * Kst + kBase + sx0;
    const bf16* ga11 = A + (size_t)(rowBase + 128 + r1) * Kst + kBase + sx1;
    const bf16* gb00 = Bt + (size_t)(colBase + r0) * Kst + kBase + sx0;
    const bf16* gb01 = Bt + (size_t)(colBase + r1) * Kst + kBase + sx1;
    const bf16* gb10 = Bt + (size_t)(colBase + 128 + r0) * Kst + kBase + sx0;
    const bf16* gb11 = Bt + (size_t)(colBase + 128 + r1) * Kst + kBase + sx1;
    const int dOff = tid * 8;  // linear LDS dest (elems)

    f32x4 acc[8][4];
#pragma unroll
    for (int i = 0; i < 8; i++)
#pragma unroll
        for (int j = 0; j < 4; j++) acc[i][j] = (f32x4){0.f, 0.f, 0.f, 0.f};
    bfx8 af[4][2], bf[4][2];

    // prologue: A(0), B(0), B(1); allow B(1)'s 4 loads to stay in flight
    STG_A(0, 0, 0); STG_A(0, 1, 0); STG_B(0, 0, 0); STG_B(0, 1, 0);
    STG_B(1, 0, 1); STG_B(1, 1, 1);
    asm volatile("s_waitcnt vmcnt(4)" ::: "memory");
    __builtin_amdgcn_s_barrier();

    const int nPairs = NT >> 1;
    for (int it = 0; it < nPairs; ++it) {
        int u1 = 2 * it + 1;
        int u2 = 2 * it + 2; if (u2 > NT - 1) u2 = NT - 1;  // tail clamp: restage
        int u3 = 2 * it + 3; if (u3 > NT - 1) u3 = NT - 1;  // of identical bytes
        KTILE(0, u1, u2);
        KTILE(1, u2, u3);
    }

    // ---- write own partial slice (C/D layout col=lane&15, row=quad*4+reg) ----
    bf16* Ps = P + (size_t)bz * (size_t)sStride;
#pragma unroll
    for (int i = 0; i < 8; i++) {
#pragma unroll
        for (int j = 0; j < 4; j++) {
#pragma unroll
            for (int r = 0; r < 4; r++) {
                int grow = rowBase + wr + i * 16 + quad * 4 + r;
                int gcol = colBase + wc + j * 16 + lcol;
                Ps[(size_t)grow * ldc + gcol] = __float2bfloat16(acc[i][j][r]);
            }
        }
    }
    if (flags == nullptr) return;  // non-fused fallback

    // ---- last-block-wins combine ----
    __threadfence();  // release: partial stores visible before flag bump
    int* lastP = (int*)&SM[4096];  // byte 8192; clear of wscL (bytes 0..1024)
    if (tid == 0) lastP[0] = (atomicAdd(&flags[by * nx + bx], 1) == NZ - 1) ? 1 : 0;
    __syncthreads();
    if (lastP[0] == 0) return;
    __threadfence();  // acquire: see other blocks' partials

    if (MODE == 4) {
        float* wscL = (float*)&SM[0];
        if (tid < 256) {
            int e = colBase + tid;
            wscL[tid] = sv1[e] / (sv2[e] + 1e-8f);
        }
        __syncthreads();
#pragma unroll 4
        for (int rep = 0; rep < 16; rep++) {
            int idx = rep * 512 + tid;
            int row = idx >> 5, ch = idx & 31;
            size_t off = (size_t)(rowBase + row) * ldc + colBase + ch * 8;
            bfx8 p0 = *(const bfx8*)&P[off];
            bfx8 p1 = *(const bfx8*)&P[(size_t)sStride + off];
            bfx8 p2 = *(const bfx8*)&P[2 * (size_t)sStride + off];
            bfx8 p3 = *(const bfx8*)&P[3 * (size_t)sStride + off];
            bfx8 o;
#pragma unroll
            for (int q = 0; q < 8; q++)
                o[q] = (__bf16)((((float)p0[q] + (float)p1[q]) + ((float)p2[q] + (float)p3[q])) *
                                wscL[ch * 8 + q]);
            *(bfx8*)&ttOut[off] = o;
        }
    } else {
#pragma unroll 4
        for (int rep = 0; rep < 16; rep++) {
            int idx = rep * 512 + tid;
            int row = idx >> 5, ch = idx & 31;
            int n = rowBase + row;
            float dv = rsqrtf(sv1[n] + 1e-8f);
            size_t poff = (size_t)n * ldc + colBase + ch * 8;
            bfx8 a = *(const bfx8*)&P[poff];
            bfx8 b2 = *(const bfx8*)&P[(size_t)sStride + poff];
            size_t ooff = (size_t)(colBase >> 8) * 1048576 + (size_t)n * 256 + ch * 8;
            f32x4 w0, w1;
#pragma unroll
            for (int t = 0; t < 4; t++) {
                w0[t] = dv * ((float)a[t] + (float)b2[t]);
                w1[t] = dv * ((float)a[4 + t] + (float)b2[4 + t]);
            }
            *(f32x4*)&outF[ooff] = w0;
            *(f32x4*)&outF[ooff + 4] = w1;
        }
    }
}

// ---------------------------------------------------------------------------
// dst[C][R] = src[R][C]^T, 64x64 tiles (HT[e][n] -> Hb[n][e]) — fallback only
__global__ void transpose_kernel(const bf16* __restrict__ src, bf16* __restrict__ dst,
                                 int R, int C) {
    __shared__ __bf16 t[64][68];
    int cb = blockIdx.x * 64, rb = blockIdx.y * 64;
    int tid = threadIdx.x;
    int lc = tid & 7, lr = tid >> 3;
#pragma unroll
    for (int p = 0; p < 2; p++) {
        int r = lr + p * 32;
        bfx8 v = *(const bfx8*)&src[(size_t)(rb + r) * C + cb + lc * 8];
#pragma unroll
        for (int q = 0; q < 8; q++) t[r][lc * 8 + q] = v[q];
    }
    __syncthreads();
#pragma unroll
    for (int p = 0; p < 2; p++) {
        int c = lr + p * 32;
        bfx8 v;
#pragma unroll
        for (int q = 0; q < 8; q++) v[q] = t[lc * 8 + q][c];
        *(bfx8*)&dst[(size_t)(cb + c) * R + rb + lc * 8] = v;
    }
}

// out[b][n][o] = rsqrt(dvr[n]+eps) * (sA + sB)   — fallback only
__global__ void combine_out_kernel(const bf16* __restrict__ sA, const bf16* __restrict__ sB,
                                   const float* __restrict__ dvr, float* __restrict__ out) {
    size_t t8 = ((size_t)blockIdx.x * 256 + threadIdx.x) * 8;
    int n = (int)((t8 >> 8) & 4095);
    int b = (int)(t8 >> 20);
    int o = (int)(t8 & 255);
    size_t si = (size_t)n * 2048 + b * 256 + o;
    bfx8 a = *(const bfx8*)&sA[si];
    bfx8 bb = *(const bfx8*)&sB[si];
    float d = rsqrtf(dvr[n] + 1e-8f);
    f32x4 v0, v1;
#pragma unroll
    for (int t = 0; t < 4; t++) {
        v0[t] = d * ((float)a[t] + (float)bb[t]);
        v1[t] = d * ((float)a[4 + t] + (float)bb[4 + t]);
    }
    *(f32x4*)&out[t8] = v0;
    *(f32x4*)&out[t8 + 4] = v1;
}

// ---------------------------------------------------------------------------
extern "C" void kernel_launch(void* const* d_in, const int* in_sizes, int n_in,
                              void* d_out, int out_size, void* d_ws, size_t ws_size,
                              hipStream_t stream) {
    const float* x    = (const float*)d_in[0];  // [8,4096,256]
    const float* ew   = (const float*)d_in[1];  // [2048]
    const float* H    = (const float*)d_in[2];  // [4096,2048]
    const float* W    = (const float*)d_in[3];  // [256,256]
    const float* bias = (const float*)d_in[4];  // [256]

    const int N = 4096, E = 2048;

    // ws: de 8K | dvr 16K | flags4 (64 int) @24576 | flags5 (128 int) @25088 |
    //     HT 16MB @64K | xs_t 16MB | t_t 8MB | Hb 16MB (if room)
    char* ws = (char*)d_ws;
    float* de     = (float*)(ws);
    float* dvr    = (float*)(ws + 8192);
    int*   flags4 = (int*)(ws + 24576);
    int*   flags5 = (int*)(ws + 25088);
    bf16*  HT   = (bf16*)(ws + 65536);                 // [E][N] 16 MB
    bf16*  xs_t = (bf16*)(ws + 65536 + 16777216);      // [2048][4096] 16 MB (dead after K4)
    bf16*  t_t  = (bf16*)(ws + 65536 + 33554432);      // [2048][2048]  8 MB
    bf16*  wsHb = (bf16*)(ws + 65536 + 41943040);      // [N][E] 16 MB (primary path)
    const bool bigws = ws_size >= 58785792ull + 4096ull;

    // d_out (32 MiB): K4 partials s0..s3 (4 x 8MB) -> dead -> final f32 out.
    bf16* s0 = (bf16*)d_out;
    // K5 partials: HT slot + xs_t slot (contiguous, stride 8388608 elems)
    bf16* k5a = HT;
    bf16* k5b = xs_t;

    (void)hipMemsetAsync(ws, 0, 25600, stream);  // de + dvr + flags

    prep_kernel<<<dim3(E / 64, N / 64), 256, 0, stream>>>(
        H, ew, HT, bigws ? wsHb : nullptr, de, dvr, N, E);

    // K3: xs_t = (x W^T + b) * dv_is  (256x64 tiles, x read once)
    gemm_k3<<<dim3(64, 8), 256, 0, stream>>>(W, x, bias, dvr, xs_t);

    // K4 split-K=4 + fused combine: t_t[c][e] = (sum_z partial) * ew/(de+eps)
    gemm8ph<4><<<dim3(8, 8, 4), 512, 0, stream>>>(
        xs_t, HT, 4096, 1024, s0, 4194304LL, 2048, flags4, ew, de, t_t, nullptr);

    bf16* HbP = bigws ? wsHb : (bf16*)d_out;
    if (!bigws) {
        // fallback: build Hb from HT (K4 partials in d_out are dead now)
        transpose_kernel<<<dim3(64, 32), 256, 0, stream>>>(HT, HbP, 2048, 4096);
    }

    // K5 split-K=2 + fused combine: out = rsqrt(dvr+eps) * (sum_z partial).
    // Fused only when Hb is NOT in d_out (fused path writes d_out during K5).
    gemm8ph<5><<<dim3(8, 16, 2), 512, 0, stream>>>(
        HbP, t_t, 2048, 1024, k5a, 8388608LL, 2048,
        bigws ? flags5 : nullptr, dvr, nullptr, nullptr, (float*)d_out);

    if (!bigws) {
        combine_out_kernel<<<dim3(4096), 256, 0, stream>>>(k5a, k5b, dvr, (float*)d_out);
    }
}

// Round 5
// 220.217 us; speedup vs baseline: 1.9286x; 1.9286x over previous
//
#include <hip/hip_runtime.h>
#include <hip/hip_bf16.h>

typedef __hip_bfloat16 bf16;
typedef __bf16 bfx8 __attribute__((ext_vector_type(8)));
typedef float f32x4 __attribute__((ext_vector_type(4)));

typedef __attribute__((address_space(3))) void lds_void_t;
typedef const __attribute__((address_space(1))) void gbl_void_t;

// ---------------------------------------------------------------------------
// Fused prep: HT[e][n] = bf16(H[n][e]); optional Hb[n][e] = bf16(H[n][e]);
// de[e] += colsum; dvr[n] += row.w
__global__ void prep_kernel(const float* __restrict__ H, const float* __restrict__ w,
                            bf16* __restrict__ HT, bf16* __restrict__ Hb,
                            float* __restrict__ de, float* __restrict__ dvr, int N, int E) {
    __shared__ bf16 tile[64][65];
    __shared__ float cred[4][64];
    __shared__ float rred[4][64];
    int eb = blockIdx.x * 64, nb = blockIdx.y * 64;
    int tid = threadIdx.x;
    int c = tid & 63, g = tid >> 6;

    float cs = 0.f;
#pragma unroll
    for (int k = 0; k < 16; k++) {
        int r = g + (k << 2);
        float v = H[(size_t)(nb + r) * E + eb + c];
        bf16 bv = __float2bfloat16(v);
        tile[r][c] = bv;
        if (Hb) Hb[(size_t)(nb + r) * E + eb + c] = bv;  // row-major copy (coalesced in e)
        cs += v;
    }
    cred[g][c] = cs;
    __syncthreads();
    if (g == 0) {
        float s = cred[0][c] + cred[1][c] + cred[2][c] + cred[3][c];
        atomicAdd(&de[eb + c], s);
    }
    float rs = 0.f;
#pragma unroll
    for (int k = 0; k < 16; k++) {
        int cc = g + (k << 2);
        rs += __bfloat162float(tile[c][cc]) * w[eb + cc];
    }
    rred[g][c] = rs;
    __syncthreads();
    if (g == 1) {
        float s = rred[0][c] + rred[1][c] + rred[2][c] + rred[3][c];
        atomicAdd(&dvr[nb + c], s);
    }
#pragma unroll
    for (int k = 0; k < 16; k++) {
        int r = g + (k << 2);
        HT[(size_t)(eb + r) * N + nb + c] = tile[c][r];  // transposed (coalesced in n)
    }
}

// ---------------------------------------------------------------------------
// K3: xs_t[z*256+o][n] = (sum_d W[o][d]*x[z][n][d] + bias[o]) * rsqrt(dvr[n]+eps)
// 256x64 tile (o x n), grid (64, 8) = 512 blocks (2/CU); x read exactly once.
__global__ __launch_bounds__(256) void gemm_k3(
    const float* __restrict__ W, const float* __restrict__ x,
    const float* __restrict__ bias, const float* __restrict__ dvr,
    bf16* __restrict__ xs_t) {
    __shared__ __align__(16) bf16 As[256 * 40];  // W: 256 o x 32 k (+8 pad)
    __shared__ __align__(16) bf16 Bs[64 * 40];   // x: 64 n x 32 k

    const int bx = blockIdx.x, z = blockIdx.y;
    const int tid = threadIdx.x;
    const int wave = tid >> 6, lane = tid & 63;
    const int wr = wave * 64;  // o-rows of this wave
    const int lcol = lane & 15, quad = lane >> 4;
    const float* xp = x + (size_t)z * 1048576 + (size_t)bx * 64 * 256;

    f32x4 acc[4][4];
#pragma unroll
    for (int i = 0; i < 4; i++)
#pragma unroll
        for (int j = 0; j < 4; j++) acc[i][j] = (f32x4){0.f, 0.f, 0.f, 0.f};

    for (int k0 = 0; k0 < 256; k0 += 32) {
#pragma unroll
        for (int c = 0; c < 4; c++) {  // A (W): 8192 elems, 4 chunks/thread
            int ch = tid + c * 256;
            int r = ch >> 2, kc = (ch & 3) << 3;
            f32x4 p0 = *(const f32x4*)&W[(size_t)r * 256 + k0 + kc];
            f32x4 p1 = *(const f32x4*)&W[(size_t)r * 256 + k0 + kc + 4];
            bfx8 va;
#pragma unroll
            for (int t = 0; t < 4; t++) { va[t] = (__bf16)p0[t]; va[4 + t] = (__bf16)p1[t]; }
            *(bfx8*)&As[r * 40 + kc] = va;
        }
        {  // B (x): 2048 elems, 1 chunk/thread
            int r = tid >> 2, kc = (tid & 3) << 3;
            f32x4 q0 = *(const f32x4*)&xp[(size_t)r * 256 + k0 + kc];
            f32x4 q1 = *(const f32x4*)&xp[(size_t)r * 256 + k0 + kc + 4];
            bfx8 vb;
#pragma unroll
            for (int t = 0; t < 4; t++) { vb[t] = (__bf16)q0[t]; vb[4 + t] = (__bf16)q1[t]; }
            *(bfx8*)&Bs[r * 40 + kc] = vb;
        }
        __syncthreads();

        bfx8 af[4], bfr[4];
#pragma unroll
        for (int i = 0; i < 4; i++)
            af[i] = *(const bfx8*)&As[(wr + i * 16 + lcol) * 40 + quad * 8];
#pragma unroll
        for (int j = 0; j < 4; j++)
            bfr[j] = *(const bfx8*)&Bs[(j * 16 + lcol) * 40 + quad * 8];
#pragma unroll
        for (int i = 0; i < 4; i++)
#pragma unroll
            for (int j = 0; j < 4; j++)
                acc[i][j] = __builtin_amdgcn_mfma_f32_16x16x32_bf16(af[i], bfr[j], acc[i][j], 0, 0, 0);
        __syncthreads();
    }

#pragma unroll
    for (int j = 0; j < 4; j++) {
        int n = bx * 64 + j * 16 + lcol;
        float dn = rsqrtf(dvr[n] + 1e-8f);
#pragma unroll
        for (int i = 0; i < 4; i++) {
#pragma unroll
            for (int r = 0; r < 4; r++) {
                int o = wr + i * 16 + quad * 4 + r;
                float v = (acc[i][j][r] + bias[o]) * dn;
                xs_t[(size_t)(z * 256 + o) * 4096 + n] = __float2bfloat16(v);
            }
        }
    }
}

// ---------------------------------------------------------------------------
// 256x256 8-phase GEMM (T1+T2+T3+T4+T5), BK=64, 8 waves (2Mx4N), 512 thr.
// B^T form. Split-K via blockIdx.z -> S{0..3}. LDS 128 KiB, XOR swizzle
// both-sides (rule 21). ROUND-2 stage rotation (best measured): per K-tile u
// P1:A0(u+1) P2:A1(u+1) (opposite buf) P3:B0(u+2) P4:B1(u+2) (same buf, B
// reads retired at P2-end barrier). vmcnt(4) once per tile at P4 -> A(u+1)
// and B(u+1) landed, B(u+2)'s 4 loads stay in flight. Never vmcnt(0) in loop.
// NO fused cross-block combine: device-scope __threadfence on gfx950 forces
// per-XCD L2 writeback/invalidate per block -> measured 4.3x slowdown (R4).

#define STG_A(cb, h, u) do { \
    __builtin_amdgcn_global_load_lds((gbl_void_t*)(ga##h##0 + (size_t)(u) * 64), \
        (lds_void_t*)&SM[(cb) * 16384 + (h) * 8192 + dOff], 16, 0, 0); \
    __builtin_amdgcn_global_load_lds((gbl_void_t*)(ga##h##1 + (size_t)(u) * 64), \
        (lds_void_t*)&SM[(cb) * 16384 + (h) * 8192 + 4096 + dOff], 16, 0, 0); \
} while (0)

#define STG_B(cb, h, u) do { \
    __builtin_amdgcn_global_load_lds((gbl_void_t*)(gb##h##0 + (size_t)(u) * 64), \
        (lds_void_t*)&SM[32768 + (cb) * 16384 + (h) * 8192 + dOff], 16, 0, 0); \
    __builtin_amdgcn_global_load_lds((gbl_void_t*)(gb##h##1 + (size_t)(u) * 64), \
        (lds_void_t*)&SM[32768 + (cb) * 16384 + (h) * 8192 + 4096 + dOff], 16, 0, 0); \
} while (0)

#define LDA_(cb, qi, i, kk) \
    (*(const bfx8*)&SM[(cb) * 16384 + aBase + ((qi) * 64 + (i) * 16) * 64 + ra##kk])
#define LDB_(cb, j, kk) \
    (*(const bfx8*)&SM[32768 + (cb) * 16384 + bjb[j] + ra##kk])

#define PH_MFMA(I0, J0) do { \
    __builtin_amdgcn_s_setprio(1); \
    _Pragma("unroll") \
    for (int i_ = 0; i_ < 4; i_++) { \
        _Pragma("unroll") \
        for (int jj_ = 0; jj_ < 2; jj_++) { \
            acc[(I0) + i_][(J0) + jj_] = __builtin_amdgcn_mfma_f32_16x16x32_bf16( \
                af[i_][0], bf[(J0) + jj_][0], acc[(I0) + i_][(J0) + jj_], 0, 0, 0); \
            acc[(I0) + i_][(J0) + jj_] = __builtin_amdgcn_mfma_f32_16x16x32_bf16( \
                af[i_][1], bf[(J0) + jj_][1], acc[(I0) + i_][(J0) + jj_], 0, 0, 0); \
        } \
    } \
    __builtin_amdgcn_s_setprio(0); \
} while (0)

#define KTILE(cb, uA, uB) do { \
    /* P1: A-quad0 + B j01 reads, stage A0(next, buf cb^1) */ \
    _Pragma("unroll") \
    for (int i_ = 0; i_ < 4; i_++) { af[i_][0] = LDA_(cb, 0, i_, 0); af[i_][1] = LDA_(cb, 0, i_, 1); } \
    _Pragma("unroll") \
    for (int j_ = 0; j_ < 2; j_++) { bf[j_][0] = LDB_(cb, j_, 0); bf[j_][1] = LDB_(cb, j_, 1); } \
    STG_A((cb) ^ 1, 0, uA); \
    __builtin_amdgcn_s_barrier(); \
    PH_MFMA(0, 0); \
    __builtin_amdgcn_s_barrier(); \
    /* P2: B j23 reads, stage A1(next) */ \
    _Pragma("unroll") \
    for (int j_ = 0; j_ < 2; j_++) { bf[2 + j_][0] = LDB_(cb, 2 + j_, 0); bf[2 + j_][1] = LDB_(cb, 2 + j_, 1); } \
    STG_A((cb) ^ 1, 1, uA); \
    __builtin_amdgcn_s_barrier(); \
    PH_MFMA(0, 2); \
    __builtin_amdgcn_s_barrier(); \
    /* P3: A-quad1 reads, stage B0(u+2) into current buf (B reads retired) */ \
    _Pragma("unroll") \
    for (int i_ = 0; i_ < 4; i_++) { af[i_][0] = LDA_(cb, 1, i_, 0); af[i_][1] = LDA_(cb, 1, i_, 1); } \
    STG_B(cb, 0, uB); \
    __builtin_amdgcn_s_barrier(); \
    PH_MFMA(4, 2); \
    __builtin_amdgcn_s_barrier(); \
    /* P4: stage B1(u+2); counted vmcnt once per K-tile */ \
    STG_B(cb, 1, uB); \
    __builtin_amdgcn_s_barrier(); \
    PH_MFMA(4, 0); \
    asm volatile("s_waitcnt vmcnt(4)" ::: "memory"); \
    __builtin_amdgcn_s_barrier(); \
} while (0)

__global__ __launch_bounds__(512, 2) void gemm8ph(
    const bf16* __restrict__ A, const bf16* __restrict__ Bt, int Kst, int kLen,
    bf16* __restrict__ S0, bf16* __restrict__ S1, bf16* __restrict__ S2, bf16* __restrict__ S3,
    int ldc) {
    __shared__ __align__(16) bf16 SM[65536];  // 128 KiB

    // XCD-bijective swizzle (nwg % 8 == 0 for both launch shapes)
    const int nx = gridDim.x, ny = gridDim.y;
    const int nwg = nx * ny * gridDim.z;
    const int lin = (blockIdx.z * ny + blockIdx.y) * nx + blockIdx.x;
    const int cpx = nwg >> 3;
    const int swz = (lin & 7) * cpx + (lin >> 3);
    const int bx = swz % nx;
    const int t1 = swz / nx;
    const int by = t1 % ny;
    const int bz = t1 / ny;
    bf16* Cs = (bz == 0) ? S0 : (bz == 1) ? S1 : (bz == 2) ? S2 : S3;
    const int kBase = bz * kLen;
    const int NT = kLen >> 6;

    const int tid = threadIdx.x;
    const int lane = tid & 63, wave = tid >> 6;
    const int lcol = lane & 15, quad = lane >> 4;
    const int wr = (wave >> 2) * 128, wc = (wave & 3) * 64;
    const int aBase = (wave >> 2) * 8192;  // A half this wave reads
    const int xr = lcol & 7;               // read-side xor (== rowInHalf & 7)

    const int rowBase = by * 256, colBase = bx * 256;

    // fragment read offsets (bf16 elems): row*64 + (slot^xr)*8
    const int ra0 = lcol * 64 + ((quad ^ xr) << 3);
    const int ra1 = lcol * 64 + (((4 + quad) ^ xr) << 3);
    int bjb[4];
#pragma unroll
    for (int j = 0; j < 4; j++) {
        int rg = wc + j * 16;
        bjb[j] = ((rg >> 7) * 8192) + ((rg & 127) * 64);
    }

    // staging: thread t -> (row = t/8 + l*64, 16B-slot = t&7) per half-tile;
    // global source pre-swizzled: element col = (slot ^ (row&7))*8
    const int srow = tid >> 3, slot = tid & 7;
    const int r0 = srow, r1 = srow + 64;
    const int sx0 = (slot ^ (r0 & 7)) << 3;
    const int sx1 = (slot ^ (r1 & 7)) << 3;
    const bf16* ga00 = A + (size_t)(rowBase + r0) * Kst + kBase + sx0;
    const bf16* ga01 = A + (size_t)(rowBase + r1) * Kst + kBase + sx1;
    const bf16* ga10 = A + (size_t)(rowBase + 128 + r0) * Kst + kBase + sx0;
    const bf16* ga11 = A + (size_t)(rowBase + 128 + r1) * Kst + kBase + sx1;
    const bf16* gb00 = Bt + (size_t)(colBase + r0) * Kst + kBase + sx0;
    const bf16* gb01 = Bt + (size_t)(colBase + r1) * Kst + kBase + sx1;
    const bf16* gb10 = Bt + (size_t)(colBase + 128 + r0) * Kst + kBase + sx0;
    const bf16* gb11 = Bt + (size_t)(colBase + 128 + r1) * Kst + kBase + sx1;
    const int dOff = tid * 8;  // linear LDS dest (elems)

    f32x4 acc[8][4];
#pragma unroll
    for (int i = 0; i < 8; i++)
#pragma unroll
        for (int j = 0; j < 4; j++) acc[i][j] = (f32x4){0.f, 0.f, 0.f, 0.f};
    bfx8 af[4][2], bf[4][2];

    // prologue: A(0), B(0), B(1); allow B(1)'s 4 loads to stay in flight
    STG_A(0, 0, 0); STG_A(0, 1, 0); STG_B(0, 0, 0); STG_B(0, 1, 0);
    STG_B(1, 0, 1); STG_B(1, 1, 1);
    asm volatile("s_waitcnt vmcnt(4)" ::: "memory");
    __builtin_amdgcn_s_barrier();

    const int nPairs = NT >> 1;
    for (int it = 0; it < nPairs; ++it) {
        int u1 = 2 * it + 1;
        int u2 = 2 * it + 2; if (u2 > NT - 1) u2 = NT - 1;  // tail clamp: restage
        int u3 = 2 * it + 3; if (u3 > NT - 1) u3 = NT - 1;  // of identical bytes
        KTILE(0, u1, u2);
        KTILE(1, u2, u3);
    }

    // epilogue: C/D layout col=lane&15, row=quad*4+reg (verified m89/m91)
#pragma unroll
    for (int i = 0; i < 8; i++) {
#pragma unroll
        for (int j = 0; j < 4; j++) {
#pragma unroll
            for (int r = 0; r < 4; r++) {
                int grow = rowBase + wr + i * 16 + quad * 4 + r;
                int gcol = colBase + wc + j * 16 + lcol;
                Cs[(size_t)grow * ldc + gcol] = __float2bfloat16(acc[i][j][r]);
            }
        }
    }
}

// ---------------------------------------------------------------------------
// t_t[c][e] = bf16((s0+s1+s2+s3) * w[e]/(de[e]+eps));  [2048][2048]
__global__ void combine4_kernel(const bf16* __restrict__ s0, const bf16* __restrict__ s1,
                                const bf16* __restrict__ s2, const bf16* __restrict__ s3,
                                const float* __restrict__ w, const float* __restrict__ de,
                                bf16* __restrict__ tt) {
    size_t i = ((size_t)blockIdx.x * 256 + threadIdx.x) * 8;
    int e = (int)(i & 2047);
    bfx8 a = *(const bfx8*)&s0[i];
    bfx8 b = *(const bfx8*)&s1[i];
    bfx8 c = *(const bfx8*)&s2[i];
    bfx8 d = *(const bfx8*)&s3[i];
    bfx8 v;
#pragma unroll
    for (int t = 0; t < 8; t++) {
        float ws = w[e + t] / (de[e + t] + 1e-8f);
        v[t] = (__bf16)((((float)a[t] + (float)b[t]) + ((float)c[t] + (float)d[t])) * ws);
    }
    *(bfx8*)&tt[i] = v;
}

// dst[C][R] = src[R][C]^T, 64x64 tiles (HT[e][n] -> Hb[n][e]) — fallback only
__global__ void transpose_kernel(const bf16* __restrict__ src, bf16* __restrict__ dst,
                                 int R, int C) {
    __shared__ __bf16 t[64][68];
    int cb = blockIdx.x * 64, rb = blockIdx.y * 64;
    int tid = threadIdx.x;
    int lc = tid & 7, lr = tid >> 3;
#pragma unroll
    for (int p = 0; p < 2; p++) {
        int r = lr + p * 32;
        bfx8 v = *(const bfx8*)&src[(size_t)(rb + r) * C + cb + lc * 8];
#pragma unroll
        for (int q = 0; q < 8; q++) t[r][lc * 8 + q] = v[q];
    }
    __syncthreads();
#pragma unroll
    for (int p = 0; p < 2; p++) {
        int c = lr + p * 32;
        bfx8 v;
#pragma unroll
        for (int q = 0; q < 8; q++) v[q] = t[lc * 8 + q][c];
        *(bfx8*)&dst[(size_t)(cb + c) * R + rb + lc * 8] = v;
    }
}

// out[b][n][o] = rsqrt(dvr[n]+eps) * (sA[n][b*256+o] + sB[n][b*256+o])
__global__ void combine_out_kernel(const bf16* __restrict__ sA, const bf16* __restrict__ sB,
                                   const float* __restrict__ dvr, float* __restrict__ out) {
    size_t t8 = ((size_t)blockIdx.x * 256 + threadIdx.x) * 8;
    int o = (int)(t8 & 255);
    int n = (int)((t8 >> 8) & 4095);
    int b = (int)(t8 >> 20);
    size_t si = (size_t)n * 2048 + b * 256 + o;
    bfx8 a = *(const bfx8*)&sA[si];
    bfx8 bb = *(const bfx8*)&sB[si];
    float d = rsqrtf(dvr[n] + 1e-8f);
    f32x4 v0, v1;
#pragma unroll
    for (int t = 0; t < 4; t++) {
        v0[t] = d * ((float)a[t] + (float)bb[t]);
        v1[t] = d * ((float)a[4 + t] + (float)bb[4 + t]);
    }
    *(f32x4*)&out[t8] = v0;
    *(f32x4*)&out[t8 + 4] = v1;
}

// ---------------------------------------------------------------------------
extern "C" void kernel_launch(void* const* d_in, const int* in_sizes, int n_in,
                              void* d_out, int out_size, void* d_ws, size_t ws_size,
                              hipStream_t stream) {
    const float* x    = (const float*)d_in[0];  // [8,4096,256]
    const float* ew   = (const float*)d_in[1];  // [2048]
    const float* H    = (const float*)d_in[2];  // [4096,2048]
    const float* W    = (const float*)d_in[3];  // [256,256]
    const float* bias = (const float*)d_in[4];  // [256]

    const int N = 4096, E = 2048;

    // ws layout: hdr 64KB | HT 16MB | xs_t 16MB | t_t 8MB | Hb 16MB (if room)
    char* ws = (char*)d_ws;
    float* de   = (float*)(ws);         // 2048 f32
    float* dvr  = (float*)(ws + 8192);  // 4096 f32
    bf16*  HT   = (bf16*)(ws + 65536);                 // [E][N] 16 MB
    bf16*  xs_t = (bf16*)(ws + 65536 + 16777216);      // [2048][4096] 16 MB (dead after K4)
    bf16*  t_t  = (bf16*)(ws + 65536 + 33554432);      // [2048][2048]  8 MB
    bf16*  wsHb = (bf16*)(ws + 65536 + 41943040);      // [N][E] 16 MB (primary path)
    const bool bigws = ws_size >= 58785792ull + 4096ull;

    // d_out (32 MiB) scratch timeline:
    //  K4:       s0..s3 = 4 x 8MB bf16 split-K slices (whole d_out)
    //  fallback: transpose writes Hb to d_out[0:16M) after combine4
    //  combine:  final f32 out overwrites everything
    bf16* s0 = (bf16*)d_out;
    bf16* s1 = s0 + 4194304;
    bf16* s2 = s0 + 2 * 4194304;
    bf16* s3 = s0 + 3 * 4194304;
    bf16* k5a = HT;    // K5 slice 0 (HT slot, dead after K4)
    bf16* k5b = xs_t;  // K5 slice 1 (xs_t slot, dead after K4)

    (void)hipMemsetAsync(ws, 0, 24576, stream);  // de + dvr

    prep_kernel<<<dim3(E / 64, N / 64), 256, 0, stream>>>(
        H, ew, HT, bigws ? wsHb : nullptr, de, dvr, N, E);

    // K3: xs_t = (x W^T + b) * dv_is  (256x64 tiles, x read once)
    gemm_k3<<<dim3(64, 8), 256, 0, stream>>>(W, x, bias, dvr, xs_t);

    // K4 split-K=4: s[z][c][e] = sum_{n in z-quarter} xs_t[c][n] * HT[e][n]
    gemm8ph<<<dim3(8, 8, 4), 512, 0, stream>>>(xs_t, HT, 4096, 1024, s0, s1, s2, s3, 2048);

    // t_t = bf16((s0+s1+s2+s3) * w/(de+eps))
    combine4_kernel<<<dim3(2048), 256, 0, stream>>>(s0, s1, s2, s3, ew, de, t_t);

    bf16* HbP = bigws ? wsHb : (bf16*)d_out;
    if (!bigws) {
        // fallback: build Hb from HT now that slices are consumed
        transpose_kernel<<<dim3(64, 32), 256, 0, stream>>>(HT, HbP, 2048, 4096);
    }

    // K5 split-K=2: slice[z][n][c] = sum_{e in z-half} Hb[n][e] * t_t[c][e]
    gemm8ph<<<dim3(8, 16, 2), 512, 0, stream>>>(HbP, t_t, 2048, 1024, k5a, k5b, k5a, k5a, 2048);

    // out[b][n][o] = rsqrt(dvr[n]+eps) * (k5a + k5b)
    combine_out_kernel<<<dim3(4096), 256, 0, stream>>>(k5a, k5b, dvr, (float*)d_out);
}

// Round 6
// 218.003 us; speedup vs baseline: 1.9482x; 1.0102x over previous
//
#include <hip/hip_runtime.h>
#include <hip/hip_bf16.h>

typedef __hip_bfloat16 bf16;
typedef __bf16 bfx8 __attribute__((ext_vector_type(8)));
typedef float f32x4 __attribute__((ext_vector_type(4)));

typedef __attribute__((address_space(3))) void lds_void_t;
typedef const __attribute__((address_space(1))) void gbl_void_t;

// ---------------------------------------------------------------------------
// Fused prep: HT[e][n] = bf16(H[n][e]); optional Hb[n][e] = bf16(H[n][e]);
// de[e] += colsum; dvr[n] += row.w
__global__ void prep_kernel(const float* __restrict__ H, const float* __restrict__ w,
                            bf16* __restrict__ HT, bf16* __restrict__ Hb,
                            float* __restrict__ de, float* __restrict__ dvr, int N, int E) {
    __shared__ bf16 tile[64][65];
    __shared__ float cred[4][64];
    __shared__ float rred[4][64];
    int eb = blockIdx.x * 64, nb = blockIdx.y * 64;
    int tid = threadIdx.x;
    int c = tid & 63, g = tid >> 6;

    float cs = 0.f;
#pragma unroll
    for (int k = 0; k < 16; k++) {
        int r = g + (k << 2);
        float v = H[(size_t)(nb + r) * E + eb + c];
        bf16 bv = __float2bfloat16(v);
        tile[r][c] = bv;
        if (Hb) Hb[(size_t)(nb + r) * E + eb + c] = bv;  // row-major copy (coalesced in e)
        cs += v;
    }
    cred[g][c] = cs;
    __syncthreads();
    if (g == 0) {
        float s = cred[0][c] + cred[1][c] + cred[2][c] + cred[3][c];
        atomicAdd(&de[eb + c], s);
    }
    float rs = 0.f;
#pragma unroll
    for (int k = 0; k < 16; k++) {
        int cc = g + (k << 2);
        rs += __bfloat162float(tile[c][cc]) * w[eb + cc];
    }
    rred[g][c] = rs;
    __syncthreads();
    if (g == 1) {
        float s = rred[0][c] + rred[1][c] + rred[2][c] + rred[3][c];
        atomicAdd(&dvr[nb + c], s);
    }
#pragma unroll
    for (int k = 0; k < 16; k++) {
        int r = g + (k << 2);
        HT[(size_t)(eb + r) * N + nb + c] = tile[c][r];  // transposed (coalesced in n)
    }
}

// ---------------------------------------------------------------------------
// K3: xs_t[z*256+o][n] = (sum_d W[o][d]*x[z][n][d] + bias[o]) * rsqrt(dvr[n]+eps)
// 256x64 tile (o x n), grid (64, 8) = 512 blocks (2/CU); x read exactly once.
__global__ __launch_bounds__(256) void gemm_k3(
    const float* __restrict__ W, const float* __restrict__ x,
    const float* __restrict__ bias, const float* __restrict__ dvr,
    bf16* __restrict__ xs_t) {
    __shared__ __align__(16) bf16 As[256 * 40];  // W: 256 o x 32 k (+8 pad)
    __shared__ __align__(16) bf16 Bs[64 * 40];   // x: 64 n x 32 k

    const int bx = blockIdx.x, z = blockIdx.y;
    const int tid = threadIdx.x;
    const int wave = tid >> 6, lane = tid & 63;
    const int wr = wave * 64;  // o-rows of this wave
    const int lcol = lane & 15, quad = lane >> 4;
    const float* xp = x + (size_t)z * 1048576 + (size_t)bx * 64 * 256;

    f32x4 acc[4][4];
#pragma unroll
    for (int i = 0; i < 4; i++)
#pragma unroll
        for (int j = 0; j < 4; j++) acc[i][j] = (f32x4){0.f, 0.f, 0.f, 0.f};

    for (int k0 = 0; k0 < 256; k0 += 32) {
#pragma unroll
        for (int c = 0; c < 4; c++) {  // A (W): 8192 elems, 4 chunks/thread
            int ch = tid + c * 256;
            int r = ch >> 2, kc = (ch & 3) << 3;
            f32x4 p0 = *(const f32x4*)&W[(size_t)r * 256 + k0 + kc];
            f32x4 p1 = *(const f32x4*)&W[(size_t)r * 256 + k0 + kc + 4];
            bfx8 va;
#pragma unroll
            for (int t = 0; t < 4; t++) { va[t] = (__bf16)p0[t]; va[4 + t] = (__bf16)p1[t]; }
            *(bfx8*)&As[r * 40 + kc] = va;
        }
        {  // B (x): 2048 elems, 1 chunk/thread
            int r = tid >> 2, kc = (tid & 3) << 3;
            f32x4 q0 = *(const f32x4*)&xp[(size_t)r * 256 + k0 + kc];
            f32x4 q1 = *(const f32x4*)&xp[(size_t)r * 256 + k0 + kc + 4];
            bfx8 vb;
#pragma unroll
            for (int t = 0; t < 4; t++) { vb[t] = (__bf16)q0[t]; vb[4 + t] = (__bf16)q1[t]; }
            *(bfx8*)&Bs[r * 40 + kc] = vb;
        }
        __syncthreads();

        bfx8 af[4], bfr[4];
#pragma unroll
        for (int i = 0; i < 4; i++)
            af[i] = *(const bfx8*)&As[(wr + i * 16 + lcol) * 40 + quad * 8];
#pragma unroll
        for (int j = 0; j < 4; j++)
            bfr[j] = *(const bfx8*)&Bs[(j * 16 + lcol) * 40 + quad * 8];
#pragma unroll
        for (int i = 0; i < 4; i++)
#pragma unroll
            for (int j = 0; j < 4; j++)
                acc[i][j] = __builtin_amdgcn_mfma_f32_16x16x32_bf16(af[i], bfr[j], acc[i][j], 0, 0, 0);
        __syncthreads();
    }

#pragma unroll
    for (int j = 0; j < 4; j++) {
        int n = bx * 64 + j * 16 + lcol;
        float dn = rsqrtf(dvr[n] + 1e-8f);
#pragma unroll
        for (int i = 0; i < 4; i++) {
#pragma unroll
            for (int r = 0; r < 4; r++) {
                int o = wr + i * 16 + quad * 4 + r;
                float v = (acc[i][j][r] + bias[o]) * dn;
                xs_t[(size_t)(z * 256 + o) * 4096 + n] = __float2bfloat16(v);
            }
        }
    }
}

// ---------------------------------------------------------------------------
// 256x256 8-phase GEMM, BK=64, 8 waves (2Mx4N), 512 thr. B^T form. Split-K
// via blockIdx.z -> S{0..3}. LDS 128 KiB, XOR swizzle both-sides (rule 21).
// R2 stage rotation: P1:A0(u+1) P2:A1(u+1) (opposite buf) P3:B0(u+2)
// P4:B1(u+2) (same buf, B reads retired at P2-end barrier). vmcnt(4) once
// per tile at P4. Never vmcnt(0) in loop.
//
// R6 barrier-reduction (8 -> 6 barriers/K-tile): post-MFMA barriers of P1
// and P3 are provably redundant for THIS rotation -- every stage's last
// reader is separated from the stage by a remaining barrier:
//   P1/P2 A(u+1)-stages: last A-reads were prev tile P1/P3, completed at
//     prev-P4's pre-MFMA barrier (each wave's MFMA forces its lgkm drain).
//   P3/P4 B(u+2)-stages: last B-reads were P2, gated by P2's KEPT
//     post-MFMA barrier.
// Replaced with zero-cost compiler fences (pin compile-time order; waves
// may drift one phase at runtime -> MFMA/stage overlap across waves).
// NO cross-block fences: __threadfence => per-XCD L2 flush, 4.3x (R4).

#define STG_A(cb, h, u) do { \
    __builtin_amdgcn_global_load_lds((gbl_void_t*)(ga##h##0 + (size_t)(u) * 64), \
        (lds_void_t*)&SM[(cb) * 16384 + (h) * 8192 + dOff], 16, 0, 0); \
    __builtin_amdgcn_global_load_lds((gbl_void_t*)(ga##h##1 + (size_t)(u) * 64), \
        (lds_void_t*)&SM[(cb) * 16384 + (h) * 8192 + 4096 + dOff], 16, 0, 0); \
} while (0)

#define STG_B(cb, h, u) do { \
    __builtin_amdgcn_global_load_lds((gbl_void_t*)(gb##h##0 + (size_t)(u) * 64), \
        (lds_void_t*)&SM[32768 + (cb) * 16384 + (h) * 8192 + dOff], 16, 0, 0); \
    __builtin_amdgcn_global_load_lds((gbl_void_t*)(gb##h##1 + (size_t)(u) * 64), \
        (lds_void_t*)&SM[32768 + (cb) * 16384 + (h) * 8192 + 4096 + dOff], 16, 0, 0); \
} while (0)

#define LDA_(cb, qi, i, kk) \
    (*(const bfx8*)&SM[(cb) * 16384 + aBase + ((qi) * 64 + (i) * 16) * 64 + ra##kk])
#define LDB_(cb, j, kk) \
    (*(const bfx8*)&SM[32768 + (cb) * 16384 + bjb[j] + ra##kk])

#define PH_MFMA(I0, J0) do { \
    __builtin_amdgcn_s_setprio(1); \
    _Pragma("unroll") \
    for (int i_ = 0; i_ < 4; i_++) { \
        _Pragma("unroll") \
        for (int jj_ = 0; jj_ < 2; jj_++) { \
            acc[(I0) + i_][(J0) + jj_] = __builtin_amdgcn_mfma_f32_16x16x32_bf16( \
                af[i_][0], bf[(J0) + jj_][0], acc[(I0) + i_][(J0) + jj_], 0, 0, 0); \
            acc[(I0) + i_][(J0) + jj_] = __builtin_amdgcn_mfma_f32_16x16x32_bf16( \
                af[i_][1], bf[(J0) + jj_][1], acc[(I0) + i_][(J0) + jj_], 0, 0, 0); \
        } \
    } \
    __builtin_amdgcn_s_setprio(0); \
} while (0)

#define CFENCE asm volatile("" ::: "memory")

#define KTILE(cb, uA, uB) do { \
    /* P1: A-quad0 + B j01 reads, stage A0(next, buf cb^1) */ \
    _Pragma("unroll") \
    for (int i_ = 0; i_ < 4; i_++) { af[i_][0] = LDA_(cb, 0, i_, 0); af[i_][1] = LDA_(cb, 0, i_, 1); } \
    _Pragma("unroll") \
    for (int j_ = 0; j_ < 2; j_++) { bf[j_][0] = LDB_(cb, j_, 0); bf[j_][1] = LDB_(cb, j_, 1); } \
    STG_A((cb) ^ 1, 0, uA); \
    __builtin_amdgcn_s_barrier(); \
    PH_MFMA(0, 0); \
    CFENCE;  /* was barrier: redundant (see header) */ \
    /* P2: B j23 reads, stage A1(next) */ \
    _Pragma("unroll") \
    for (int j_ = 0; j_ < 2; j_++) { bf[2 + j_][0] = LDB_(cb, 2 + j_, 0); bf[2 + j_][1] = LDB_(cb, 2 + j_, 1); } \
    STG_A((cb) ^ 1, 1, uA); \
    __builtin_amdgcn_s_barrier(); \
    PH_MFMA(0, 2); \
    __builtin_amdgcn_s_barrier();  /* KEPT: gates P3/P4 B-stages vs P1/P2 B-reads */ \
    /* P3: A-quad1 reads, stage B0(u+2) into current buf */ \
    _Pragma("unroll") \
    for (int i_ = 0; i_ < 4; i_++) { af[i_][0] = LDA_(cb, 1, i_, 0); af[i_][1] = LDA_(cb, 1, i_, 1); } \
    STG_B(cb, 0, uB); \
    __builtin_amdgcn_s_barrier(); \
    PH_MFMA(4, 2); \
    CFENCE;  /* was barrier: redundant (see header) */ \
    /* P4: stage B1(u+2); counted vmcnt once per K-tile */ \
    STG_B(cb, 1, uB); \
    __builtin_amdgcn_s_barrier(); \
    PH_MFMA(4, 0); \
    asm volatile("s_waitcnt vmcnt(4)" ::: "memory"); \
    __builtin_amdgcn_s_barrier(); \
} while (0)

__global__ __launch_bounds__(512, 2) void gemm8ph(
    const bf16* __restrict__ A, const bf16* __restrict__ Bt, int Kst, int kLen,
    bf16* __restrict__ S0, bf16* __restrict__ S1, bf16* __restrict__ S2, bf16* __restrict__ S3,
    int ldc) {
    __shared__ __align__(16) bf16 SM[65536];  // 128 KiB

    // XCD-bijective swizzle (nwg % 8 == 0 for both launch shapes)
    const int nx = gridDim.x, ny = gridDim.y;
    const int nwg = nx * ny * gridDim.z;
    const int lin = (blockIdx.z * ny + blockIdx.y) * nx + blockIdx.x;
    const int cpx = nwg >> 3;
    const int swz = (lin & 7) * cpx + (lin >> 3);
    const int bx = swz % nx;
    const int t1 = swz / nx;
    const int by = t1 % ny;
    const int bz = t1 / ny;
    bf16* Cs = (bz == 0) ? S0 : (bz == 1) ? S1 : (bz == 2) ? S2 : S3;
    const int kBase = bz * kLen;
    const int NT = kLen >> 6;

    const int tid = threadIdx.x;
    const int lane = tid & 63, wave = tid >> 6;
    const int lcol = lane & 15, quad = lane >> 4;
    const int wr = (wave >> 2) * 128, wc = (wave & 3) * 64;
    const int aBase = (wave >> 2) * 8192;  // A half this wave reads
    const int xr = lcol & 7;               // read-side xor (== rowInHalf & 7)

    const int rowBase = by * 256, colBase = bx * 256;

    // fragment read offsets (bf16 elems): row*64 + (slot^xr)*8
    const int ra0 = lcol * 64 + ((quad ^ xr) << 3);
    const int ra1 = lcol * 64 + (((4 + quad) ^ xr) << 3);
    int bjb[4];
#pragma unroll
    for (int j = 0; j < 4; j++) {
        int rg = wc + j * 16;
        bjb[j] = ((rg >> 7) * 8192) + ((rg & 127) * 64);
    }

    // staging: thread t -> (row = t/8 + l*64, 16B-slot = t&7) per half-tile;
    // global source pre-swizzled: element col = (slot ^ (row&7))*8
    const int srow = tid >> 3, slot = tid & 7;
    const int r0 = srow, r1 = srow + 64;
    const int sx0 = (slot ^ (r0 & 7)) << 3;
    const int sx1 = (slot ^ (r1 & 7)) << 3;
    const bf16* ga00 = A + (size_t)(rowBase + r0) * Kst + kBase + sx0;
    const bf16* ga01 = A + (size_t)(rowBase + r1) * Kst + kBase + sx1;
    const bf16* ga10 = A + (size_t)(rowBase + 128 + r0) * Kst + kBase + sx0;
    const bf16* ga11 = A + (size_t)(rowBase + 128 + r1) * Kst + kBase + sx1;
    const bf16* gb00 = Bt + (size_t)(colBase + r0) * Kst + kBase + sx0;
    const bf16* gb01 = Bt + (size_t)(colBase + r1) * Kst + kBase + sx1;
    const bf16* gb10 = Bt + (size_t)(colBase + 128 + r0) * Kst + kBase + sx0;
    const bf16* gb11 = Bt + (size_t)(colBase + 128 + r1) * Kst + kBase + sx1;
    const int dOff = tid * 8;  // linear LDS dest (elems)

    f32x4 acc[8][4];
#pragma unroll
    for (int i = 0; i < 8; i++)
#pragma unroll
        for (int j = 0; j < 4; j++) acc[i][j] = (f32x4){0.f, 0.f, 0.f, 0.f};
    bfx8 af[4][2], bf[4][2];

    // prologue: A(0), B(0), B(1); allow B(1)'s 4 loads to stay in flight
    STG_A(0, 0, 0); STG_A(0, 1, 0); STG_B(0, 0, 0); STG_B(0, 1, 0);
    STG_B(1, 0, 1); STG_B(1, 1, 1);
    asm volatile("s_waitcnt vmcnt(4)" ::: "memory");
    __builtin_amdgcn_s_barrier();

    const int nPairs = NT >> 1;
    for (int it = 0; it < nPairs; ++it) {
        int u1 = 2 * it + 1;
        int u2 = 2 * it + 2; if (u2 > NT - 1) u2 = NT - 1;  // tail clamp: restage
        int u3 = 2 * it + 3; if (u3 > NT - 1) u3 = NT - 1;  // of identical bytes
        KTILE(0, u1, u2);
        KTILE(1, u2, u3);
    }

    // epilogue: C/D layout col=lane&15, row=quad*4+reg (verified m89/m91)
#pragma unroll
    for (int i = 0; i < 8; i++) {
#pragma unroll
        for (int j = 0; j < 4; j++) {
#pragma unroll
            for (int r = 0; r < 4; r++) {
                int grow = rowBase + wr + i * 16 + quad * 4 + r;
                int gcol = colBase + wc + j * 16 + lcol;
                Cs[(size_t)grow * ldc + gcol] = __float2bfloat16(acc[i][j][r]);
            }
        }
    }
}

// ---------------------------------------------------------------------------
// t_t[c][e] = bf16((s0+s1+s2+s3) * w[e]/(de[e]+eps));  [2048][2048]
__global__ void combine4_kernel(const bf16* __restrict__ s0, const bf16* __restrict__ s1,
                                const bf16* __restrict__ s2, const bf16* __restrict__ s3,
                                const float* __restrict__ w, const float* __restrict__ de,
                                bf16* __restrict__ tt) {
    size_t i = ((size_t)blockIdx.x * 256 + threadIdx.x) * 8;
    int e = (int)(i & 2047);
    bfx8 a = *(const bfx8*)&s0[i];
    bfx8 b = *(const bfx8*)&s1[i];
    bfx8 c = *(const bfx8*)&s2[i];
    bfx8 d = *(const bfx8*)&s3[i];
    bfx8 v;
#pragma unroll
    for (int t = 0; t < 8; t++) {
        float ws = w[e + t] / (de[e + t] + 1e-8f);
        v[t] = (__bf16)((((float)a[t] + (float)b[t]) + ((float)c[t] + (float)d[t])) * ws);
    }
    *(bfx8*)&tt[i] = v;
}

// dst[C][R] = src[R][C]^T, 64x64 tiles (HT[e][n] -> Hb[n][e]) — fallback only
__global__ void transpose_kernel(const bf16* __restrict__ src, bf16* __restrict__ dst,
                                 int R, int C) {
    __shared__ __bf16 t[64][68];
    int cb = blockIdx.x * 64, rb = blockIdx.y * 64;
    int tid = threadIdx.x;
    int lc = tid & 7, lr = tid >> 3;
#pragma unroll
    for (int p = 0; p < 2; p++) {
        int r = lr + p * 32;
        bfx8 v = *(const bfx8*)&src[(size_t)(rb + r) * C + cb + lc * 8];
#pragma unroll
        for (int q = 0; q < 8; q++) t[r][lc * 8 + q] = v[q];
    }
    __syncthreads();
#pragma unroll
    for (int p = 0; p < 2; p++) {
        int c = lr + p * 32;
        bfx8 v;
#pragma unroll
        for (int q = 0; q < 8; q++) v[q] = t[lc * 8 + q][c];
        *(bfx8*)&dst[(size_t)(cb + c) * R + rb + lc * 8] = v;
    }
}

// out[b][n][o] = rsqrt(dvr[n]+eps) * (sA[n][b*256+o] + sB[n][b*256+o])
__global__ void combine_out_kernel(const bf16* __restrict__ sA, const bf16* __restrict__ sB,
                                   const float* __restrict__ dvr, float* __restrict__ out) {
    size_t t8 = ((size_t)blockIdx.x * 256 + threadIdx.x) * 8;
    int o = (int)(t8 & 255);
    int n = (int)((t8 >> 8) & 4095);
    int b = (int)(t8 >> 20);
    size_t si = (size_t)n * 2048 + b * 256 + o;
    bfx8 a = *(const bfx8*)&sA[si];
    bfx8 bb = *(const bfx8*)&sB[si];
    float d = rsqrtf(dvr[n] + 1e-8f);
    f32x4 v0, v1;
#pragma unroll
    for (int t = 0; t < 4; t++) {
        v0[t] = d * ((float)a[t] + (float)bb[t]);
        v1[t] = d * ((float)a[4 + t] + (float)bb[4 + t]);
    }
    *(f32x4*)&out[t8] = v0;
    *(f32x4*)&out[t8 + 4] = v1;
}

// ---------------------------------------------------------------------------
extern "C" void kernel_launch(void* const* d_in, const int* in_sizes, int n_in,
                              void* d_out, int out_size, void* d_ws, size_t ws_size,
                              hipStream_t stream) {
    const float* x    = (const float*)d_in[0];  // [8,4096,256]
    const float* ew   = (const float*)d_in[1];  // [2048]
    const float* H    = (const float*)d_in[2];  // [4096,2048]
    const float* W    = (const float*)d_in[3];  // [256,256]
    const float* bias = (const float*)d_in[4];  // [256]

    const int N = 4096, E = 2048;

    // ws layout: hdr 64KB | HT 16MB | xs_t 16MB | t_t 8MB | Hb 16MB (if room)
    char* ws = (char*)d_ws;
    float* de   = (float*)(ws);         // 2048 f32
    float* dvr  = (float*)(ws + 8192);  // 4096 f32
    bf16*  HT   = (bf16*)(ws + 65536);                 // [E][N] 16 MB
    bf16*  xs_t = (bf16*)(ws + 65536 + 16777216);      // [2048][4096] 16 MB (dead after K4)
    bf16*  t_t  = (bf16*)(ws + 65536 + 33554432);      // [2048][2048]  8 MB
    bf16*  wsHb = (bf16*)(ws + 65536 + 41943040);      // [N][E] 16 MB (primary path)
    const bool bigws = ws_size >= 58785792ull + 4096ull;

    // d_out (32 MiB) scratch timeline:
    //  K4:       s0..s3 = 4 x 8MB bf16 split-K slices (whole d_out)
    //  fallback: transpose writes Hb to d_out[0:16M) after combine4
    //  combine:  final f32 out overwrites everything
    bf16* s0 = (bf16*)d_out;
    bf16* s1 = s0 + 4194304;
    bf16* s2 = s0 + 2 * 4194304;
    bf16* s3 = s0 + 3 * 4194304;
    bf16* k5a = HT;    // K5 slice 0 (HT slot, dead after K4)
    bf16* k5b = xs_t;  // K5 slice 1 (xs_t slot, dead after K4)

    (void)hipMemsetAsync(ws, 0, 24576, stream);  // de + dvr

    prep_kernel<<<dim3(E / 64, N / 64), 256, 0, stream>>>(
        H, ew, HT, bigws ? wsHb : nullptr, de, dvr, N, E);

    // K3: xs_t = (x W^T + b) * dv_is  (256x64 tiles, x read once)
    gemm_k3<<<dim3(64, 8), 256, 0, stream>>>(W, x, bias, dvr, xs_t);

    // K4 split-K=4: s[z][c][e] = sum_{n in z-quarter} xs_t[c][n] * HT[e][n]
    gemm8ph<<<dim3(8, 8, 4), 512, 0, stream>>>(xs_t, HT, 4096, 1024, s0, s1, s2, s3, 2048);

    // t_t = bf16((s0+s1+s2+s3) * w/(de+eps))
    combine4_kernel<<<dim3(2048), 256, 0, stream>>>(s0, s1, s2, s3, ew, de, t_t);

    bf16* HbP = bigws ? wsHb : (bf16*)d_out;
    if (!bigws) {
        // fallback: build Hb from HT now that slices are consumed
        transpose_kernel<<<dim3(64, 32), 256, 0, stream>>>(HT, HbP, 2048, 4096);
    }

    // K5 split-K=2: slice[z][n][c] = sum_{e in z-half} Hb[n][e] * t_t[c][e]
    gemm8ph<<<dim3(8, 16, 2), 512, 0, stream>>>(HbP, t_t, 2048, 1024, k5a, k5b, k5a, k5a, 2048);

    // out[b][n][o] = rsqrt(dvr[n]+eps) * (k5a + k5b)
    combine_out_kernel<<<dim3(4096), 256, 0, stream>>>(k5a, k5b, dvr, (float*)d_out);
}

// Round 8
// 198.623 us; speedup vs baseline: 2.1383x; 1.0976x over previous
//
#include <hip/hip_runtime.h>
#include <hip/hip_bf16.h>

typedef __hip_bfloat16 bf16;
typedef __bf16 bfx8 __attribute__((ext_vector_type(8)));
typedef __bf16 bfx4 __attribute__((ext_vector_type(4)));
typedef float f32x4 __attribute__((ext_vector_type(4)));

typedef __attribute__((address_space(3))) void lds_void_t;
typedef const __attribute__((address_space(1))) void gbl_void_t;

// ---------------------------------------------------------------------------
// Fused prep (float4 reads, 8B writes, single sync):
// HT[e][n] = bf16(H[n][e]); Hb[n][e] = bf16(H[n][e]); de/dvr accumulated.
__global__ void prep_kernel(const float* __restrict__ H, const float* __restrict__ w,
                            bf16* __restrict__ HT, bf16* __restrict__ Hb,
                            float* __restrict__ de, float* __restrict__ dvr, int N, int E) {
    __shared__ __align__(8) __bf16 tile[64][68];  // stride 136B: 8B-aligned rows
    int eb = blockIdx.x * 64, nb = blockIdx.y * 64;
    int tid = threadIdx.x;
    int lane = tid & 63, g = tid >> 6;
    int cq = (lane & 15) * 4;            // 4-col group
    int rbase = g + ((lane >> 4) << 2);  // rows rbase + 16m, m=0..3

#pragma unroll
    for (int m = 0; m < 4; m++) {
        int r = rbase + (m << 4);
        f32x4 v = *(const f32x4*)&H[(size_t)(nb + r) * E + eb + cq];
        bfx4 b4;
#pragma unroll
        for (int t = 0; t < 4; t++) b4[t] = (__bf16)v[t];
        *(bfx4*)&tile[r][cq] = b4;
        if (Hb) *(bfx4*)&Hb[(size_t)(nb + r) * E + eb + cq] = b4;
    }
    __syncthreads();

    int c = lane;
    if (g == 0) {  // de[e]: column sums (binary -> bf16 exact)
        float s = 0.f;
#pragma unroll 8
        for (int rr = 0; rr < 64; rr++) s += (float)tile[rr][c];
        atomicAdd(&de[eb + c], s);
    } else if (g == 1) {  // dvr[n]: row . w
        float s = 0.f;
#pragma unroll 8
        for (int cc = 0; cc < 64; cc++) s += (float)tile[c][cc] * w[eb + cc];
        atomicAdd(&dvr[nb + c], s);
    }
#pragma unroll
    for (int k = 0; k < 16; k++) {
        int r = g + (k << 2);
        HT[(size_t)(eb + r) * N + nb + c] = (bf16)tile[c][r];  // transposed
    }
}

// ---------------------------------------------------------------------------
// K3: xs_t[z*256+o][n] = (sum_d W[o][d]*x[z][n][d] + bias[o]) * rsqrt(dvr[n]+eps)
__global__ __launch_bounds__(256) void gemm_k3(
    const float* __restrict__ W, const float* __restrict__ x,
    const float* __restrict__ bias, const float* __restrict__ dvr,
    bf16* __restrict__ xs_t) {
    __shared__ __align__(16) bf16 As[256 * 40];
    __shared__ __align__(16) bf16 Bs[64 * 40];

    const int bx = blockIdx.x, z = blockIdx.y;
    const int tid = threadIdx.x;
    const int wave = tid >> 6, lane = tid & 63;
    const int wr = wave * 64;
    const int lcol = lane & 15, quad = lane >> 4;
    const float* xp = x + (size_t)z * 1048576 + (size_t)bx * 64 * 256;

    f32x4 acc[4][4];
#pragma unroll
    for (int i = 0; i < 4; i++)
#pragma unroll
        for (int j = 0; j < 4; j++) acc[i][j] = (f32x4){0.f, 0.f, 0.f, 0.f};

    for (int k0 = 0; k0 < 256; k0 += 32) {
#pragma unroll
        for (int c = 0; c < 4; c++) {
            int ch = tid + c * 256;
            int r = ch >> 2, kc = (ch & 3) << 3;
            f32x4 p0 = *(const f32x4*)&W[(size_t)r * 256 + k0 + kc];
            f32x4 p1 = *(const f32x4*)&W[(size_t)r * 256 + k0 + kc + 4];
            bfx8 va;
#pragma unroll
            for (int t = 0; t < 4; t++) { va[t] = (__bf16)p0[t]; va[4 + t] = (__bf16)p1[t]; }
            *(bfx8*)&As[r * 40 + kc] = va;
        }
        {
            int r = tid >> 2, kc = (tid & 3) << 3;
            f32x4 q0 = *(const f32x4*)&xp[(size_t)r * 256 + k0 + kc];
            f32x4 q1 = *(const f32x4*)&xp[(size_t)r * 256 + k0 + kc + 4];
            bfx8 vb;
#pragma unroll
            for (int t = 0; t < 4; t++) { vb[t] = (__bf16)q0[t]; vb[4 + t] = (__bf16)q1[t]; }
            *(bfx8*)&Bs[r * 40 + kc] = vb;
        }
        __syncthreads();

        bfx8 af[4], bfr[4];
#pragma unroll
        for (int i = 0; i < 4; i++)
            af[i] = *(const bfx8*)&As[(wr + i * 16 + lcol) * 40 + quad * 8];
#pragma unroll
        for (int j = 0; j < 4; j++)
            bfr[j] = *(const bfx8*)&Bs[(j * 16 + lcol) * 40 + quad * 8];
#pragma unroll
        for (int i = 0; i < 4; i++)
#pragma unroll
            for (int j = 0; j < 4; j++)
                acc[i][j] = __builtin_amdgcn_mfma_f32_16x16x32_bf16(af[i], bfr[j], acc[i][j], 0, 0, 0);
        __syncthreads();
    }

#pragma unroll
    for (int j = 0; j < 4; j++) {
        int n = bx * 64 + j * 16 + lcol;
        float dn = rsqrtf(dvr[n] + 1e-8f);
#pragma unroll
        for (int i = 0; i < 4; i++) {
#pragma unroll
            for (int r = 0; r < 4; r++) {
                int o = wr + i * 16 + quad * 4 + r;
                float v = (acc[i][j][r] + bias[o]) * dn;
                xs_t[(size_t)(z * 256 + o) * 4096 + n] = __float2bfloat16(v);
            }
        }
    }
}

// ---------------------------------------------------------------------------
// 256x256 8-phase GEMM (K4 + fallback K5). R6 6-barrier schedule (best).
#define STG_A(cb, h, u) do { \
    __builtin_amdgcn_global_load_lds((gbl_void_t*)(ga##h##0 + (size_t)(u) * 64), \
        (lds_void_t*)&SM[(cb) * 16384 + (h) * 8192 + dOff], 16, 0, 0); \
    __builtin_amdgcn_global_load_lds((gbl_void_t*)(ga##h##1 + (size_t)(u) * 64), \
        (lds_void_t*)&SM[(cb) * 16384 + (h) * 8192 + 4096 + dOff], 16, 0, 0); \
} while (0)

#define STG_B(cb, h, u) do { \
    __builtin_amdgcn_global_load_lds((gbl_void_t*)(gb##h##0 + (size_t)(u) * 64), \
        (lds_void_t*)&SM[32768 + (cb) * 16384 + (h) * 8192 + dOff], 16, 0, 0); \
    __builtin_amdgcn_global_load_lds((gbl_void_t*)(gb##h##1 + (size_t)(u) * 64), \
        (lds_void_t*)&SM[32768 + (cb) * 16384 + (h) * 8192 + 4096 + dOff], 16, 0, 0); \
} while (0)

#define LDA_(cb, qi, i, kk) \
    (*(const bfx8*)&SM[(cb) * 16384 + aBase + ((qi) * 64 + (i) * 16) * 64 + ra##kk])
#define LDB_(cb, j, kk) \
    (*(const bfx8*)&SM[32768 + (cb) * 16384 + bjb[j] + ra##kk])

#define PH_MFMA(I0, J0) do { \
    __builtin_amdgcn_s_setprio(1); \
    _Pragma("unroll") \
    for (int i_ = 0; i_ < 4; i_++) { \
        _Pragma("unroll") \
        for (int jj_ = 0; jj_ < 2; jj_++) { \
            acc[(I0) + i_][(J0) + jj_] = __builtin_amdgcn_mfma_f32_16x16x32_bf16( \
                af[i_][0], bf[(J0) + jj_][0], acc[(I0) + i_][(J0) + jj_], 0, 0, 0); \
            acc[(I0) + i_][(J0) + jj_] = __builtin_amdgcn_mfma_f32_16x16x32_bf16( \
                af[i_][1], bf[(J0) + jj_][1], acc[(I0) + i_][(J0) + jj_], 0, 0, 0); \
        } \
    } \
    __builtin_amdgcn_s_setprio(0); \
} while (0)

#define CFENCE asm volatile("" ::: "memory")

#define KTILE(cb, uA, uB) do { \
    _Pragma("unroll") \
    for (int i_ = 0; i_ < 4; i_++) { af[i_][0] = LDA_(cb, 0, i_, 0); af[i_][1] = LDA_(cb, 0, i_, 1); } \
    _Pragma("unroll") \
    for (int j_ = 0; j_ < 2; j_++) { bf[j_][0] = LDB_(cb, j_, 0); bf[j_][1] = LDB_(cb, j_, 1); } \
    STG_A((cb) ^ 1, 0, uA); \
    __builtin_amdgcn_s_barrier(); \
    PH_MFMA(0, 0); \
    CFENCE; \
    _Pragma("unroll") \
    for (int j_ = 0; j_ < 2; j_++) { bf[2 + j_][0] = LDB_(cb, 2 + j_, 0); bf[2 + j_][1] = LDB_(cb, 2 + j_, 1); } \
    STG_A((cb) ^ 1, 1, uA); \
    __builtin_amdgcn_s_barrier(); \
    PH_MFMA(0, 2); \
    __builtin_amdgcn_s_barrier(); \
    _Pragma("unroll") \
    for (int i_ = 0; i_ < 4; i_++) { af[i_][0] = LDA_(cb, 1, i_, 0); af[i_][1] = LDA_(cb, 1, i_, 1); } \
    STG_B(cb, 0, uB); \
    __builtin_amdgcn_s_barrier(); \
    PH_MFMA(4, 2); \
    CFENCE; \
    STG_B(cb, 1, uB); \
    __builtin_amdgcn_s_barrier(); \
    PH_MFMA(4, 0); \
    asm volatile("s_waitcnt vmcnt(4)" ::: "memory"); \
    __builtin_amdgcn_s_barrier(); \
} while (0)

__global__ __launch_bounds__(512, 2) void gemm8ph(
    const bf16* __restrict__ A, const bf16* __restrict__ Bt, int Kst, int kLen,
    bf16* __restrict__ S0, bf16* __restrict__ S1, bf16* __restrict__ S2, bf16* __restrict__ S3,
    int ldc) {
    __shared__ __align__(16) bf16 SM[65536];  // 128 KiB

    const int nx = gridDim.x, ny = gridDim.y;
    const int nwg = nx * ny * gridDim.z;
    const int lin = (blockIdx.z * ny + blockIdx.y) * nx + blockIdx.x;
    const int cpx = nwg >> 3;
    const int swz = (lin & 7) * cpx + (lin >> 3);
    const int bx = swz % nx;
    const int t1 = swz / nx;
    const int by = t1 % ny;
    const int bz = t1 / ny;
    bf16* Cs = (bz == 0) ? S0 : (bz == 1) ? S1 : (bz == 2) ? S2 : S3;
    const int kBase = bz * kLen;
    const int NT = kLen >> 6;

    const int tid = threadIdx.x;
    const int lane = tid & 63, wave = tid >> 6;
    const int lcol = lane & 15, quad = lane >> 4;
    const int wr = (wave >> 2) * 128, wc = (wave & 3) * 64;
    const int aBase = (wave >> 2) * 8192;
    const int xr = lcol & 7;

    const int rowBase = by * 256, colBase = bx * 256;

    const int ra0 = lcol * 64 + ((quad ^ xr) << 3);
    const int ra1 = lcol * 64 + (((4 + quad) ^ xr) << 3);
    int bjb[4];
#pragma unroll
    for (int j = 0; j < 4; j++) {
        int rg = wc + j * 16;
        bjb[j] = ((rg >> 7) * 8192) + ((rg & 127) * 64);
    }

    const int srow = tid >> 3, slot = tid & 7;
    const int r0 = srow, r1 = srow + 64;
    const int sx0 = (slot ^ (r0 & 7)) << 3;
    const int sx1 = (slot ^ (r1 & 7)) << 3;
    const bf16* ga00 = A + (size_t)(rowBase + r0) * Kst + kBase + sx0;
    const bf16* ga01 = A + (size_t)(rowBase + r1) * Kst + kBase + sx1;
    const bf16* ga10 = A + (size_t)(rowBase + 128 + r0) * Kst + kBase + sx0;
    const bf16* ga11 = A + (size_t)(rowBase + 128 + r1) * Kst + kBase + sx1;
    const bf16* gb00 = Bt + (size_t)(colBase + r0) * Kst + kBase + sx0;
    const bf16* gb01 = Bt + (size_t)(colBase + r1) * Kst + kBase + sx1;
    const bf16* gb10 = Bt + (size_t)(colBase + 128 + r0) * Kst + kBase + sx0;
    const bf16* gb11 = Bt + (size_t)(colBase + 128 + r1) * Kst + kBase + sx1;
    const int dOff = tid * 8;

    f32x4 acc[8][4];
#pragma unroll
    for (int i = 0; i < 8; i++)
#pragma unroll
        for (int j = 0; j < 4; j++) acc[i][j] = (f32x4){0.f, 0.f, 0.f, 0.f};
    bfx8 af[4][2], bf[4][2];

    STG_A(0, 0, 0); STG_A(0, 1, 0); STG_B(0, 0, 0); STG_B(0, 1, 0);
    STG_B(1, 0, 1); STG_B(1, 1, 1);
    asm volatile("s_waitcnt vmcnt(4)" ::: "memory");
    __builtin_amdgcn_s_barrier();

    const int nPairs = NT >> 1;
    for (int it = 0; it < nPairs; ++it) {
        int u1 = 2 * it + 1;
        int u2 = 2 * it + 2; if (u2 > NT - 1) u2 = NT - 1;
        int u3 = 2 * it + 3; if (u3 > NT - 1) u3 = NT - 1;
        KTILE(0, u1, u2);
        KTILE(1, u2, u3);
    }

#pragma unroll
    for (int i = 0; i < 8; i++) {
#pragma unroll
        for (int j = 0; j < 4; j++) {
#pragma unroll
            for (int r = 0; r < 4; r++) {
                int grow = rowBase + wr + i * 16 + quad * 4 + r;
                int gcol = colBase + wc + j * 16 + lcol;
                Cs[(size_t)grow * ldc + gcol] = __float2bfloat16(acc[i][j][r]);
            }
        }
    }
}

// ---------------------------------------------------------------------------
// K5: 256(n) x 128(c) tile, full K=2048 (NT=32), grid 16x16=256, no split-K.
// 8 waves (4M x 2N), per-wave 64x64, acc[4][4]. LDS 96KB: A 2x32KB | B 2x16KB.
// P1: read all af/bf from cb; stage A(u+1)->cb^1; bar; MFMA j01; bar
// P2: stage B(u+2)->cb; MFMA j23; vmcnt(2); bar
// vmcnt(2) leaves only B(u+2) in flight -> A(u+1)/B(u+1) landed at swap.
// R7 BUGFIX: LDA5/LDB5 row term must NOT add lcol (ra_kk already has lcol*64).
#define STG5_A(cb, h, u) do { \
    __builtin_amdgcn_global_load_lds((gbl_void_t*)(ga##h##0 + (size_t)(u) * 64), \
        (lds_void_t*)&SM[(cb) * 16384 + (h) * 8192 + dOff], 16, 0, 0); \
    __builtin_amdgcn_global_load_lds((gbl_void_t*)(ga##h##1 + (size_t)(u) * 64), \
        (lds_void_t*)&SM[(cb) * 16384 + (h) * 8192 + 4096 + dOff], 16, 0, 0); \
} while (0)

#define STG5_B(cb, u) do { \
    __builtin_amdgcn_global_load_lds((gbl_void_t*)(gb0 + (size_t)(u) * 64), \
        (lds_void_t*)&SM[32768 + (cb) * 8192 + dOff], 16, 0, 0); \
    __builtin_amdgcn_global_load_lds((gbl_void_t*)(gb1 + (size_t)(u) * 64), \
        (lds_void_t*)&SM[32768 + (cb) * 8192 + 4096 + dOff], 16, 0, 0); \
} while (0)

#define LDA5(cb, i, kk) \
    (*(const bfx8*)&SM[(cb) * 16384 + (wr + (i) * 16) * 64 + ra##kk])
#define LDB5(cb, j, kk) \
    (*(const bfx8*)&SM[32768 + (cb) * 8192 + (wc + (j) * 16) * 64 + ra##kk])

#define PH5_MFMA(J0) do { \
    __builtin_amdgcn_s_setprio(1); \
    _Pragma("unroll") \
    for (int i_ = 0; i_ < 4; i_++) { \
        _Pragma("unroll") \
        for (int jj_ = 0; jj_ < 2; jj_++) { \
            acc[i_][(J0) + jj_] = __builtin_amdgcn_mfma_f32_16x16x32_bf16( \
                af[i_][0], bf[(J0) + jj_][0], acc[i_][(J0) + jj_], 0, 0, 0); \
            acc[i_][(J0) + jj_] = __builtin_amdgcn_mfma_f32_16x16x32_bf16( \
                af[i_][1], bf[(J0) + jj_][1], acc[i_][(J0) + jj_], 0, 0, 0); \
        } \
    } \
    __builtin_amdgcn_s_setprio(0); \
} while (0)

#define KTILE5(cb, uA, uB) do { \
    _Pragma("unroll") \
    for (int i_ = 0; i_ < 4; i_++) { af[i_][0] = LDA5(cb, i_, 0); af[i_][1] = LDA5(cb, i_, 1); } \
    _Pragma("unroll") \
    for (int j_ = 0; j_ < 4; j_++) { bf[j_][0] = LDB5(cb, j_, 0); bf[j_][1] = LDB5(cb, j_, 1); } \
    STG5_A((cb) ^ 1, 0, uA); \
    STG5_A((cb) ^ 1, 1, uA); \
    __builtin_amdgcn_s_barrier(); \
    PH5_MFMA(0); \
    __builtin_amdgcn_s_barrier(); \
    STG5_B(cb, uB); \
    PH5_MFMA(2); \
    asm volatile("s_waitcnt vmcnt(2)" ::: "memory"); \
    __builtin_amdgcn_s_barrier(); \
} while (0)

__global__ __launch_bounds__(512, 2) void gemm_k5(
    const bf16* __restrict__ A, const bf16* __restrict__ Bt,
    const float* __restrict__ dvr, float* __restrict__ outF) {
    __shared__ __align__(16) bf16 SM[49152];  // 96 KiB
    const int Kst = 2048, NT = 32;

    const int nx = gridDim.x, ny = gridDim.y;
    const int nwg = nx * ny;
    const int lin = blockIdx.y * nx + blockIdx.x;
    const int cpx = nwg >> 3;
    const int swz = (lin & 7) * cpx + (lin >> 3);
    const int bx = swz % nx;
    const int by = swz / nx;

    const int tid = threadIdx.x;
    const int lane = tid & 63, wave = tid >> 6;
    const int lcol = lane & 15, quad = lane >> 4;
    const int wr = (wave >> 1) * 64;   // M offset in [0,256)
    const int wc = (wave & 1) * 64;    // N offset in [0,128)
    const int xr = lcol & 7;

    const int rowBase = by * 256, colBase = bx * 128;

    const int ra0 = lcol * 64 + ((quad ^ xr) << 3);
    const int ra1 = lcol * 64 + (((4 + quad) ^ xr) << 3);

    const int srow = tid >> 3, slot = tid & 7;
    const int r0 = srow, r1 = srow + 64;
    const int sx0 = (slot ^ (r0 & 7)) << 3;
    const int sx1 = (slot ^ (r1 & 7)) << 3;
    const bf16* ga00 = A + (size_t)(rowBase + r0) * Kst + sx0;
    const bf16* ga01 = A + (size_t)(rowBase + r1) * Kst + sx1;
    const bf16* ga10 = A + (size_t)(rowBase + 128 + r0) * Kst + sx0;
    const bf16* ga11 = A + (size_t)(rowBase + 128 + r1) * Kst + sx1;
    const bf16* gb0  = Bt + (size_t)(colBase + r0) * Kst + sx0;
    const bf16* gb1  = Bt + (size_t)(colBase + r1) * Kst + sx1;
    const int dOff = tid * 8;

    f32x4 acc[4][4];
#pragma unroll
    for (int i = 0; i < 4; i++)
#pragma unroll
        for (int j = 0; j < 4; j++) acc[i][j] = (f32x4){0.f, 0.f, 0.f, 0.f};
    bfx8 af[4][2], bf[4][2];

    // prologue: A(0),B(0) -> buf0; B(1) -> buf1; leave B(1)'s 2 in flight
    STG5_A(0, 0, 0); STG5_A(0, 1, 0); STG5_B(0, 0);
    STG5_B(1, 1);
    asm volatile("s_waitcnt vmcnt(2)" ::: "memory");
    __builtin_amdgcn_s_barrier();

    for (int it = 0; it < NT / 2; ++it) {
        int u0 = 2 * it, u1 = 2 * it + 1;
        int a0 = u0 + 1;
        int b0 = u0 + 2; if (b0 > NT - 1) b0 = NT - 1;
        int a1 = u1 + 1; if (a1 > NT - 1) a1 = NT - 1;
        int b1 = u1 + 2; if (b1 > NT - 1) b1 = NT - 1;
        KTILE5(0, a0, b0);
        KTILE5(1, a1, b1);
    }

    // epilogue: direct final f32 out[b][n][o], n=grow, b=gcol>>8, o=gcol&255
#pragma unroll
    for (int i = 0; i < 4; i++) {
#pragma unroll
        for (int r = 0; r < 4; r++) {
            int grow = rowBase + wr + i * 16 + quad * 4 + r;
            float dn = rsqrtf(dvr[grow] + 1e-8f);
#pragma unroll
            for (int j = 0; j < 4; j++) {
                int gcol = colBase + wc + j * 16 + lcol;
                outF[(size_t)(gcol >> 8) * 1048576 + (size_t)grow * 256 + (gcol & 255)] =
                    acc[i][j][r] * dn;
            }
        }
    }
}

// ---------------------------------------------------------------------------
// t_t[c][e] = bf16((s0+s1+s2+s3) * w[e]/(de[e]+eps));  [2048][2048]
__global__ void combine4_kernel(const bf16* __restrict__ s0, const bf16* __restrict__ s1,
                                const bf16* __restrict__ s2, const bf16* __restrict__ s3,
                                const float* __restrict__ w, const float* __restrict__ de,
                                bf16* __restrict__ tt) {
    size_t i = ((size_t)blockIdx.x * 256 + threadIdx.x) * 8;
    int e = (int)(i & 2047);
    bfx8 a = *(const bfx8*)&s0[i];
    bfx8 b = *(const bfx8*)&s1[i];
    bfx8 c = *(const bfx8*)&s2[i];
    bfx8 d = *(const bfx8*)&s3[i];
    bfx8 v;
#pragma unroll
    for (int t = 0; t < 8; t++) {
        float ws = w[e + t] / (de[e + t] + 1e-8f);
        v[t] = (__bf16)((((float)a[t] + (float)b[t]) + ((float)c[t] + (float)d[t])) * ws);
    }
    *(bfx8*)&tt[i] = v;
}

// fallback-only kernels (small-ws path)
__global__ void transpose_kernel(const bf16* __restrict__ src, bf16* __restrict__ dst,
                                 int R, int C) {
    __shared__ __bf16 t[64][68];
    int cb = blockIdx.x * 64, rb = blockIdx.y * 64;
    int tid = threadIdx.x;
    int lc = tid & 7, lr = tid >> 3;
#pragma unroll
    for (int p = 0; p < 2; p++) {
        int r = lr + p * 32;
        bfx8 v = *(const bfx8*)&src[(size_t)(rb + r) * C + cb + lc * 8];
#pragma unroll
        for (int q = 0; q < 8; q++) t[r][lc * 8 + q] = v[q];
    }
    __syncthreads();
#pragma unroll
    for (int p = 0; p < 2; p++) {
        int c = lr + p * 32;
        bfx8 v;
#pragma unroll
        for (int q = 0; q < 8; q++) v[q] = t[lc * 8 + q][c];
        *(bfx8*)&dst[(size_t)(cb + c) * R + rb + lc * 8] = v;
    }
}

__global__ void combine_out_kernel(const bf16* __restrict__ sA, const bf16* __restrict__ sB,
                                   const float* __restrict__ dvr, float* __restrict__ out) {
    size_t t8 = ((size_t)blockIdx.x * 256 + threadIdx.x) * 8;
    int n = (int)((t8 >> 8) & 4095);
    size_t si = (size_t)n * 2048 + (size_t)(t8 >> 20) * 256 + (t8 & 255);
    bfx8 a = *(const bfx8*)&sA[si];
    bfx8 bb = *(const bfx8*)&sB[si];
    float d = rsqrtf(dvr[n] + 1e-8f);
    f32x4 v0, v1;
#pragma unroll
    for (int t = 0; t < 4; t++) {
        v0[t] = d * ((float)a[t] + (float)bb[t]);
        v1[t] = d * ((float)a[4 + t] + (float)bb[4 + t]);
    }
    *(f32x4*)&out[t8] = v0;
    *(f32x4*)&out[t8 + 4] = v1;
}

// ---------------------------------------------------------------------------
extern "C" void kernel_launch(void* const* d_in, const int* in_sizes, int n_in,
                              void* d_out, int out_size, void* d_ws, size_t ws_size,
                              hipStream_t stream) {
    const float* x    = (const float*)d_in[0];
    const float* ew   = (const float*)d_in[1];
    const float* H    = (const float*)d_in[2];
    const float* W    = (const float*)d_in[3];
    const float* bias = (const float*)d_in[4];

    const int N = 4096, E = 2048;

    char* ws = (char*)d_ws;
    float* de   = (float*)(ws);
    float* dvr  = (float*)(ws + 8192);
    bf16*  HT   = (bf16*)(ws + 65536);                 // [E][N] 16 MB
    bf16*  xs_t = (bf16*)(ws + 65536 + 16777216);      // [2048][4096] 16 MB
    bf16*  t_t  = (bf16*)(ws + 65536 + 33554432);      // [2048][2048]  8 MB
    bf16*  wsHb = (bf16*)(ws + 65536 + 41943040);      // [N][E] 16 MB
    const bool bigws = ws_size >= 58785792ull + 4096ull;

    bf16* s0 = (bf16*)d_out;
    bf16* s1 = s0 + 4194304;
    bf16* s2 = s0 + 2 * 4194304;
    bf16* s3 = s0 + 3 * 4194304;

    (void)hipMemsetAsync(ws, 0, 24576, stream);  // de + dvr

    prep_kernel<<<dim3(E / 64, N / 64), 256, 0, stream>>>(
        H, ew, HT, bigws ? wsHb : nullptr, de, dvr, N, E);

    gemm_k3<<<dim3(64, 8), 256, 0, stream>>>(W, x, bias, dvr, xs_t);

    // K4 split-K=4: slices in d_out
    gemm8ph<<<dim3(8, 8, 4), 512, 0, stream>>>(xs_t, HT, 4096, 1024, s0, s1, s2, s3, 2048);

    combine4_kernel<<<dim3(2048), 256, 0, stream>>>(s0, s1, s2, s3, ew, de, t_t);

    if (bigws) {
        // K5 full-K 256x128, fused epilogue -> final f32 out (slices now dead)
        gemm_k5<<<dim3(16, 16), 512, 0, stream>>>(wsHb, t_t, dvr, (float*)d_out);
    } else {
        // fallback: old split-K path via d_out-resident Hb
        bf16* HbP = (bf16*)d_out;
        transpose_kernel<<<dim3(64, 32), 256, 0, stream>>>(HT, HbP, 2048, 4096);
        bf16* k5a = HT;
        bf16* k5b = xs_t;
        gemm8ph<<<dim3(8, 16, 2), 512, 0, stream>>>(HbP, t_t, 2048, 1024, k5a, k5b, k5a, k5a, 2048);
        combine_out_kernel<<<dim3(4096), 256, 0, stream>>>(k5a, k5b, dvr, (float*)d_out);
    }
}

// Round 9
// 197.854 us; speedup vs baseline: 2.1466x; 1.0039x over previous
//
#include <hip/hip_runtime.h>
#include <hip/hip_bf16.h>

typedef __hip_bfloat16 bf16;
typedef __bf16 bfx8 __attribute__((ext_vector_type(8)));
typedef __bf16 bfx4 __attribute__((ext_vector_type(4)));
typedef float f32x4 __attribute__((ext_vector_type(4)));

typedef __attribute__((address_space(3))) void lds_void_t;
typedef const __attribute__((address_space(1))) void gbl_void_t;

// ---------------------------------------------------------------------------
// Fused prep (float4 reads, 8B writes, single sync):
// HT[e][n] = bf16(H[n][e]); Hb[n][e] = bf16(H[n][e]); de/dvr accumulated.
__global__ void prep_kernel(const float* __restrict__ H, const float* __restrict__ w,
                            bf16* __restrict__ HT, bf16* __restrict__ Hb,
                            float* __restrict__ de, float* __restrict__ dvr, int N, int E) {
    __shared__ __align__(8) __bf16 tile[64][68];
    int eb = blockIdx.x * 64, nb = blockIdx.y * 64;
    int tid = threadIdx.x;
    int lane = tid & 63, g = tid >> 6;
    int cq = (lane & 15) * 4;
    int rbase = g + ((lane >> 4) << 2);

#pragma unroll
    for (int m = 0; m < 4; m++) {
        int r = rbase + (m << 4);
        f32x4 v = *(const f32x4*)&H[(size_t)(nb + r) * E + eb + cq];
        bfx4 b4;
#pragma unroll
        for (int t = 0; t < 4; t++) b4[t] = (__bf16)v[t];
        *(bfx4*)&tile[r][cq] = b4;
        if (Hb) *(bfx4*)&Hb[(size_t)(nb + r) * E + eb + cq] = b4;
    }
    __syncthreads();

    int c = lane;
    if (g == 0) {
        float s = 0.f;
#pragma unroll 8
        for (int rr = 0; rr < 64; rr++) s += (float)tile[rr][c];
        atomicAdd(&de[eb + c], s);
    } else if (g == 1) {
        float s = 0.f;
#pragma unroll 8
        for (int cc = 0; cc < 64; cc++) s += (float)tile[c][cc] * w[eb + cc];
        atomicAdd(&dvr[nb + c], s);
    }
#pragma unroll
    for (int k = 0; k < 16; k++) {
        int r = g + (k << 2);
        HT[(size_t)(eb + r) * N + nb + c] = (bf16)tile[c][r];
    }
}

// ---------------------------------------------------------------------------
// K3: xs_t[z*256+o][n] = (sum_d W[o][d]*x[z][n][d] + bias[o]) * rsqrt(dvr[n]+eps)
__global__ __launch_bounds__(256) void gemm_k3(
    const float* __restrict__ W, const float* __restrict__ x,
    const float* __restrict__ bias, const float* __restrict__ dvr,
    bf16* __restrict__ xs_t) {
    __shared__ __align__(16) bf16 As[256 * 40];
    __shared__ __align__(16) bf16 Bs[64 * 40];

    const int bx = blockIdx.x, z = blockIdx.y;
    const int tid = threadIdx.x;
    const int wave = tid >> 6, lane = tid & 63;
    const int wr = wave * 64;
    const int lcol = lane & 15, quad = lane >> 4;
    const float* xp = x + (size_t)z * 1048576 + (size_t)bx * 64 * 256;

    f32x4 acc[4][4];
#pragma unroll
    for (int i = 0; i < 4; i++)
#pragma unroll
        for (int j = 0; j < 4; j++) acc[i][j] = (f32x4){0.f, 0.f, 0.f, 0.f};

    for (int k0 = 0; k0 < 256; k0 += 32) {
#pragma unroll
        for (int c = 0; c < 4; c++) {
            int ch = tid + c * 256;
            int r = ch >> 2, kc = (ch & 3) << 3;
            f32x4 p0 = *(const f32x4*)&W[(size_t)r * 256 + k0 + kc];
            f32x4 p1 = *(const f32x4*)&W[(size_t)r * 256 + k0 + kc + 4];
            bfx8 va;
#pragma unroll
            for (int t = 0; t < 4; t++) { va[t] = (__bf16)p0[t]; va[4 + t] = (__bf16)p1[t]; }
            *(bfx8*)&As[r * 40 + kc] = va;
        }
        {
            int r = tid >> 2, kc = (tid & 3) << 3;
            f32x4 q0 = *(const f32x4*)&xp[(size_t)r * 256 + k0 + kc];
            f32x4 q1 = *(const f32x4*)&xp[(size_t)r * 256 + k0 + kc + 4];
            bfx8 vb;
#pragma unroll
            for (int t = 0; t < 4; t++) { vb[t] = (__bf16)q0[t]; vb[4 + t] = (__bf16)q1[t]; }
            *(bfx8*)&Bs[r * 40 + kc] = vb;
        }
        __syncthreads();

        bfx8 af[4], bfr[4];
#pragma unroll
        for (int i = 0; i < 4; i++)
            af[i] = *(const bfx8*)&As[(wr + i * 16 + lcol) * 40 + quad * 8];
#pragma unroll
        for (int j = 0; j < 4; j++)
            bfr[j] = *(const bfx8*)&Bs[(j * 16 + lcol) * 40 + quad * 8];
#pragma unroll
        for (int i = 0; i < 4; i++)
#pragma unroll
            for (int j = 0; j < 4; j++)
                acc[i][j] = __builtin_amdgcn_mfma_f32_16x16x32_bf16(af[i], bfr[j], acc[i][j], 0, 0, 0);
        __syncthreads();
    }

#pragma unroll
    for (int j = 0; j < 4; j++) {
        int n = bx * 64 + j * 16 + lcol;
        float dn = rsqrtf(dvr[n] + 1e-8f);
#pragma unroll
        for (int i = 0; i < 4; i++) {
#pragma unroll
            for (int r = 0; r < 4; r++) {
                int o = wr + i * 16 + quad * 4 + r;
                float v = (acc[i][j][r] + bias[o]) * dn;
                xs_t[(size_t)(z * 256 + o) * 4096 + n] = __float2bfloat16(v);
            }
        }
    }
}

// ---------------------------------------------------------------------------
// 256x256 8-phase GEMM — FALLBACK-ONLY now (small-ws K5 path).
#define STG_A(cb, h, u) do { \
    __builtin_amdgcn_global_load_lds((gbl_void_t*)(ga##h##0 + (size_t)(u) * 64), \
        (lds_void_t*)&SM[(cb) * 16384 + (h) * 8192 + dOff], 16, 0, 0); \
    __builtin_amdgcn_global_load_lds((gbl_void_t*)(ga##h##1 + (size_t)(u) * 64), \
        (lds_void_t*)&SM[(cb) * 16384 + (h) * 8192 + 4096 + dOff], 16, 0, 0); \
} while (0)

#define STG_B(cb, h, u) do { \
    __builtin_amdgcn_global_load_lds((gbl_void_t*)(gb##h##0 + (size_t)(u) * 64), \
        (lds_void_t*)&SM[32768 + (cb) * 16384 + (h) * 8192 + dOff], 16, 0, 0); \
    __builtin_amdgcn_global_load_lds((gbl_void_t*)(gb##h##1 + (size_t)(u) * 64), \
        (lds_void_t*)&SM[32768 + (cb) * 16384 + (h) * 8192 + 4096 + dOff], 16, 0, 0); \
} while (0)

#define LDA_(cb, qi, i, kk) \
    (*(const bfx8*)&SM[(cb) * 16384 + aBase + ((qi) * 64 + (i) * 16) * 64 + ra##kk])
#define LDB_(cb, j, kk) \
    (*(const bfx8*)&SM[32768 + (cb) * 16384 + bjb[j] + ra##kk])

#define PH_MFMA(I0, J0) do { \
    __builtin_amdgcn_s_setprio(1); \
    _Pragma("unroll") \
    for (int i_ = 0; i_ < 4; i_++) { \
        _Pragma("unroll") \
        for (int jj_ = 0; jj_ < 2; jj_++) { \
            acc[(I0) + i_][(J0) + jj_] = __builtin_amdgcn_mfma_f32_16x16x32_bf16( \
                af[i_][0], bf[(J0) + jj_][0], acc[(I0) + i_][(J0) + jj_], 0, 0, 0); \
            acc[(I0) + i_][(J0) + jj_] = __builtin_amdgcn_mfma_f32_16x16x32_bf16( \
                af[i_][1], bf[(J0) + jj_][1], acc[(I0) + i_][(J0) + jj_], 0, 0, 0); \
        } \
    } \
    __builtin_amdgcn_s_setprio(0); \
} while (0)

#define CFENCE asm volatile("" ::: "memory")

#define KTILE(cb, uA, uB) do { \
    _Pragma("unroll") \
    for (int i_ = 0; i_ < 4; i_++) { af[i_][0] = LDA_(cb, 0, i_, 0); af[i_][1] = LDA_(cb, 0, i_, 1); } \
    _Pragma("unroll") \
    for (int j_ = 0; j_ < 2; j_++) { bf[j_][0] = LDB_(cb, j_, 0); bf[j_][1] = LDB_(cb, j_, 1); } \
    STG_A((cb) ^ 1, 0, uA); \
    __builtin_amdgcn_s_barrier(); \
    PH_MFMA(0, 0); \
    CFENCE; \
    _Pragma("unroll") \
    for (int j_ = 0; j_ < 2; j_++) { bf[2 + j_][0] = LDB_(cb, 2 + j_, 0); bf[2 + j_][1] = LDB_(cb, 2 + j_, 1); } \
    STG_A((cb) ^ 1, 1, uA); \
    __builtin_amdgcn_s_barrier(); \
    PH_MFMA(0, 2); \
    __builtin_amdgcn_s_barrier(); \
    _Pragma("unroll") \
    for (int i_ = 0; i_ < 4; i_++) { af[i_][0] = LDA_(cb, 1, i_, 0); af[i_][1] = LDA_(cb, 1, i_, 1); } \
    STG_B(cb, 0, uB); \
    __builtin_amdgcn_s_barrier(); \
    PH_MFMA(4, 2); \
    CFENCE; \
    STG_B(cb, 1, uB); \
    __builtin_amdgcn_s_barrier(); \
    PH_MFMA(4, 0); \
    asm volatile("s_waitcnt vmcnt(4)" ::: "memory"); \
    __builtin_amdgcn_s_barrier(); \
} while (0)

__global__ __launch_bounds__(512, 2) void gemm8ph(
    const bf16* __restrict__ A, const bf16* __restrict__ Bt, int Kst, int kLen,
    bf16* __restrict__ S0, bf16* __restrict__ S1, bf16* __restrict__ S2, bf16* __restrict__ S3,
    int ldc) {
    __shared__ __align__(16) bf16 SM[65536];

    const int nx = gridDim.x, ny = gridDim.y;
    const int nwg = nx * ny * gridDim.z;
    const int lin = (blockIdx.z * ny + blockIdx.y) * nx + blockIdx.x;
    const int cpx = nwg >> 3;
    const int swz = (lin & 7) * cpx + (lin >> 3);
    const int bx = swz % nx;
    const int t1 = swz / nx;
    const int by = t1 % ny;
    const int bz = t1 / ny;
    bf16* Cs = (bz == 0) ? S0 : (bz == 1) ? S1 : (bz == 2) ? S2 : S3;
    const int kBase = bz * kLen;
    const int NT = kLen >> 6;

    const int tid = threadIdx.x;
    const int lane = tid & 63, wave = tid >> 6;
    const int lcol = lane & 15, quad = lane >> 4;
    const int wr = (wave >> 2) * 128, wc = (wave & 3) * 64;
    const int aBase = (wave >> 2) * 8192;
    const int xr = lcol & 7;

    const int rowBase = by * 256, colBase = bx * 256;

    const int ra0 = lcol * 64 + ((quad ^ xr) << 3);
    const int ra1 = lcol * 64 + (((4 + quad) ^ xr) << 3);
    int bjb[4];
#pragma unroll
    for (int j = 0; j < 4; j++) {
        int rg = wc + j * 16;
        bjb[j] = ((rg >> 7) * 8192) + ((rg & 127) * 64);
    }

    const int srow = tid >> 3, slot = tid & 7;
    const int r0 = srow, r1 = srow + 64;
    const int sx0 = (slot ^ (r0 & 7)) << 3;
    const int sx1 = (slot ^ (r1 & 7)) << 3;
    const bf16* ga00 = A + (size_t)(rowBase + r0) * Kst + kBase + sx0;
    const bf16* ga01 = A + (size_t)(rowBase + r1) * Kst + kBase + sx1;
    const bf16* ga10 = A + (size_t)(rowBase + 128 + r0) * Kst + kBase + sx0;
    const bf16* ga11 = A + (size_t)(rowBase + 128 + r1) * Kst + kBase + sx1;
    const bf16* gb00 = Bt + (size_t)(colBase + r0) * Kst + kBase + sx0;
    const bf16* gb01 = Bt + (size_t)(colBase + r1) * Kst + kBase + sx1;
    const bf16* gb10 = Bt + (size_t)(colBase + 128 + r0) * Kst + kBase + sx0;
    const bf16* gb11 = Bt + (size_t)(colBase + 128 + r1) * Kst + kBase + sx1;
    const int dOff = tid * 8;

    f32x4 acc[8][4];
#pragma unroll
    for (int i = 0; i < 8; i++)
#pragma unroll
        for (int j = 0; j < 4; j++) acc[i][j] = (f32x4){0.f, 0.f, 0.f, 0.f};
    bfx8 af[4][2], bf[4][2];

    STG_A(0, 0, 0); STG_A(0, 1, 0); STG_B(0, 0, 0); STG_B(0, 1, 0);
    STG_B(1, 0, 1); STG_B(1, 1, 1);
    asm volatile("s_waitcnt vmcnt(4)" ::: "memory");
    __builtin_amdgcn_s_barrier();

    const int nPairs = NT >> 1;
    for (int it = 0; it < nPairs; ++it) {
        int u1 = 2 * it + 1;
        int u2 = 2 * it + 2; if (u2 > NT - 1) u2 = NT - 1;
        int u3 = 2 * it + 3; if (u3 > NT - 1) u3 = NT - 1;
        KTILE(0, u1, u2);
        KTILE(1, u2, u3);
    }

#pragma unroll
    for (int i = 0; i < 8; i++) {
#pragma unroll
        for (int j = 0; j < 4; j++) {
#pragma unroll
            for (int r = 0; r < 4; r++) {
                int grow = rowBase + wr + i * 16 + quad * 4 + r;
                int gcol = colBase + wc + j * 16 + lcol;
                Cs[(size_t)grow * ldc + gcol] = __float2bfloat16(acc[i][j][r]);
            }
        }
    }
}

// ---------------------------------------------------------------------------
// Unified 256(row) x 128(col) 2-phase GEMM, full-kLen per z-slice.
// MODE 0 (K4): A=xs_t[c][n] Kst=4096, B=HT[e][n]; blockIdx.z in {0,1},
//   kBase=z*NT*64; writes bf16 slice Sout + z*4194304, [c][e], ldc.
// MODE 1 (K5): A=Hb[n][e] Kst=2048, B=t_t[c][e]; z=0, NT=32;
//   writes final f32 out[b][n][o] = acc * rsqrt(dvr[n]+eps).
// 8 waves (4M x 2N), per-wave 64x64, acc[4][4]. LDS 96KB: A 2x32KB | B 2x16KB.
// P1: read all af/bf from cb; stage A(u+1)->cb^1; bar; MFMA j01; bar
// P2: stage B(u+2)->cb; MFMA j23; vmcnt(2); bar   (never vmcnt(0) in loop)
// NOTE: LDA5/LDB5 row term excludes lcol (ra_kk already carries lcol*64).
#define STG5_A(cb, h, u) do { \
    __builtin_amdgcn_global_load_lds((gbl_void_t*)(ga##h##0 + (size_t)(u) * 64), \
        (lds_void_t*)&SM[(cb) * 16384 + (h) * 8192 + dOff], 16, 0, 0); \
    __builtin_amdgcn_global_load_lds((gbl_void_t*)(ga##h##1 + (size_t)(u) * 64), \
        (lds_void_t*)&SM[(cb) * 16384 + (h) * 8192 + 4096 + dOff], 16, 0, 0); \
} while (0)

#define STG5_B(cb, u) do { \
    __builtin_amdgcn_global_load_lds((gbl_void_t*)(gb0 + (size_t)(u) * 64), \
        (lds_void_t*)&SM[32768 + (cb) * 8192 + dOff], 16, 0, 0); \
    __builtin_amdgcn_global_load_lds((gbl_void_t*)(gb1 + (size_t)(u) * 64), \
        (lds_void_t*)&SM[32768 + (cb) * 8192 + 4096 + dOff], 16, 0, 0); \
} while (0)

#define LDA5(cb, i, kk) \
    (*(const bfx8*)&SM[(cb) * 16384 + (wr + (i) * 16) * 64 + ra##kk])
#define LDB5(cb, j, kk) \
    (*(const bfx8*)&SM[32768 + (cb) * 8192 + (wc + (j) * 16) * 64 + ra##kk])

#define PH5_MFMA(J0) do { \
    __builtin_amdgcn_s_setprio(1); \
    _Pragma("unroll") \
    for (int i_ = 0; i_ < 4; i_++) { \
        _Pragma("unroll") \
        for (int jj_ = 0; jj_ < 2; jj_++) { \
            acc[i_][(J0) + jj_] = __builtin_amdgcn_mfma_f32_16x16x32_bf16( \
                af[i_][0], bf[(J0) + jj_][0], acc[i_][(J0) + jj_], 0, 0, 0); \
            acc[i_][(J0) + jj_] = __builtin_amdgcn_mfma_f32_16x16x32_bf16( \
                af[i_][1], bf[(J0) + jj_][1], acc[i_][(J0) + jj_], 0, 0, 0); \
        } \
    } \
    __builtin_amdgcn_s_setprio(0); \
} while (0)

#define KTILE5(cb, uA, uB) do { \
    _Pragma("unroll") \
    for (int i_ = 0; i_ < 4; i_++) { af[i_][0] = LDA5(cb, i_, 0); af[i_][1] = LDA5(cb, i_, 1); } \
    _Pragma("unroll") \
    for (int j_ = 0; j_ < 4; j_++) { bf[j_][0] = LDB5(cb, j_, 0); bf[j_][1] = LDB5(cb, j_, 1); } \
    STG5_A((cb) ^ 1, 0, uA); \
    STG5_A((cb) ^ 1, 1, uA); \
    __builtin_amdgcn_s_barrier(); \
    PH5_MFMA(0); \
    __builtin_amdgcn_s_barrier(); \
    STG5_B(cb, uB); \
    PH5_MFMA(2); \
    asm volatile("s_waitcnt vmcnt(2)" ::: "memory"); \
    __builtin_amdgcn_s_barrier(); \
} while (0)

template <int MODE>
__global__ __launch_bounds__(512, 2) void gemm_tk(
    const bf16* __restrict__ A, const bf16* __restrict__ Bt, int Kst, int NT,
    bf16* __restrict__ Sout, int ldc,
    const float* __restrict__ dvr, float* __restrict__ outF) {
    __shared__ __align__(16) bf16 SM[49152];  // 96 KiB

    const int nx = gridDim.x, ny = gridDim.y;
    const int nwg = nx * ny * gridDim.z;
    const int lin = (blockIdx.z * ny + blockIdx.y) * nx + blockIdx.x;
    const int cpx = nwg >> 3;
    const int swz = (lin & 7) * cpx + (lin >> 3);
    const int bx = swz % nx;
    const int t1 = swz / nx;
    const int by = t1 % ny;
    const int bz = t1 / ny;
    const int kBase = bz * (NT << 6);

    const int tid = threadIdx.x;
    const int lane = tid & 63, wave = tid >> 6;
    const int lcol = lane & 15, quad = lane >> 4;
    const int wr = (wave >> 1) * 64;   // row offset in [0,256)
    const int wc = (wave & 1) * 64;    // col offset in [0,128)
    const int xr = lcol & 7;

    const int rowBase = by * 256, colBase = bx * 128;

    const int ra0 = lcol * 64 + ((quad ^ xr) << 3);
    const int ra1 = lcol * 64 + (((4 + quad) ^ xr) << 3);

    const int srow = tid >> 3, slot = tid & 7;
    const int r0 = srow, r1 = srow + 64;
    const int sx0 = (slot ^ (r0 & 7)) << 3;
    const int sx1 = (slot ^ (r1 & 7)) << 3;
    const bf16* ga00 = A + (size_t)(rowBase + r0) * Kst + kBase + sx0;
    const bf16* ga01 = A + (size_t)(rowBase + r1) * Kst + kBase + sx1;
    const bf16* ga10 = A + (size_t)(rowBase + 128 + r0) * Kst + kBase + sx0;
    const bf16* ga11 = A + (size_t)(rowBase + 128 + r1) * Kst + kBase + sx1;
    const bf16* gb0  = Bt + (size_t)(colBase + r0) * Kst + kBase + sx0;
    const bf16* gb1  = Bt + (size_t)(colBase + r1) * Kst + kBase + sx1;
    const int dOff = tid * 8;

    f32x4 acc[4][4];
#pragma unroll
    for (int i = 0; i < 4; i++)
#pragma unroll
        for (int j = 0; j < 4; j++) acc[i][j] = (f32x4){0.f, 0.f, 0.f, 0.f};
    bfx8 af[4][2], bf[4][2];

    // prologue: A(0),B(0) -> buf0; B(1) -> buf1; leave B(1)'s 2 in flight
    STG5_A(0, 0, 0); STG5_A(0, 1, 0); STG5_B(0, 0);
    STG5_B(1, 1);
    asm volatile("s_waitcnt vmcnt(2)" ::: "memory");
    __builtin_amdgcn_s_barrier();

    for (int it = 0; it < NT / 2; ++it) {
        int u0 = 2 * it, u1 = 2 * it + 1;
        int a0 = u0 + 1;
        int b0 = u0 + 2; if (b0 > NT - 1) b0 = NT - 1;
        int a1 = u1 + 1; if (a1 > NT - 1) a1 = NT - 1;
        int b1 = u1 + 2; if (b1 > NT - 1) b1 = NT - 1;
        KTILE5(0, a0, b0);
        KTILE5(1, a1, b1);
    }

    if (MODE == 0) {
        // bf16 split-K slice: S[z][row][col], slice stride 4194304 elems
        bf16* Ps = Sout + (size_t)bz * 4194304;
#pragma unroll
        for (int i = 0; i < 4; i++) {
#pragma unroll
            for (int j = 0; j < 4; j++) {
#pragma unroll
                for (int r = 0; r < 4; r++) {
                    int grow = rowBase + wr + i * 16 + quad * 4 + r;
                    int gcol = colBase + wc + j * 16 + lcol;
                    Ps[(size_t)grow * ldc + gcol] = __float2bfloat16(acc[i][j][r]);
                }
            }
        }
    } else {
        // final f32 out[b][n][o]: n=grow, b=gcol>>8, o=gcol&255
#pragma unroll
        for (int i = 0; i < 4; i++) {
#pragma unroll
            for (int r = 0; r < 4; r++) {
                int grow = rowBase + wr + i * 16 + quad * 4 + r;
                float dn = rsqrtf(dvr[grow] + 1e-8f);
#pragma unroll
                for (int j = 0; j < 4; j++) {
                    int gcol = colBase + wc + j * 16 + lcol;
                    outF[(size_t)(gcol >> 8) * 1048576 + (size_t)grow * 256 + (gcol & 255)] =
                        acc[i][j][r] * dn;
                }
            }
        }
    }
}

// ---------------------------------------------------------------------------
// t_t[c][e] = bf16((s0+s1) * w[e]/(de[e]+eps));  [2048][2048]
__global__ void combine2_kernel(const bf16* __restrict__ s0, const bf16* __restrict__ s1,
                                const float* __restrict__ w, const float* __restrict__ de,
                                bf16* __restrict__ tt) {
    size_t i = ((size_t)blockIdx.x * 256 + threadIdx.x) * 8;
    int e = (int)(i & 2047);
    bfx8 a = *(const bfx8*)&s0[i];
    bfx8 b = *(const bfx8*)&s1[i];
    bfx8 v;
#pragma unroll
    for (int t = 0; t < 8; t++) {
        float ws = w[e + t] / (de[e + t] + 1e-8f);
        v[t] = (__bf16)(((float)a[t] + (float)b[t]) * ws);
    }
    *(bfx8*)&tt[i] = v;
}

// fallback-only kernels (small-ws path)
__global__ void transpose_kernel(const bf16* __restrict__ src, bf16* __restrict__ dst,
                                 int R, int C) {
    __shared__ __bf16 t[64][68];
    int cb = blockIdx.x * 64, rb = blockIdx.y * 64;
    int tid = threadIdx.x;
    int lc = tid & 7, lr = tid >> 3;
#pragma unroll
    for (int p = 0; p < 2; p++) {
        int r = lr + p * 32;
        bfx8 v = *(const bfx8*)&src[(size_t)(rb + r) * C + cb + lc * 8];
#pragma unroll
        for (int q = 0; q < 8; q++) t[r][lc * 8 + q] = v[q];
    }
    __syncthreads();
#pragma unroll
    for (int p = 0; p < 2; p++) {
        int c = lr + p * 32;
        bfx8 v;
#pragma unroll
        for (int q = 0; q < 8; q++) v[q] = t[lc * 8 + q][c];
        *(bfx8*)&dst[(size_t)(cb + c) * R + rb + lc * 8] = v;
    }
}

__global__ void combine_out_kernel(const bf16* __restrict__ sA, const bf16* __restrict__ sB,
                                   const float* __restrict__ dvr, float* __restrict__ out) {
    size_t t8 = ((size_t)blockIdx.x * 256 + threadIdx.x) * 8;
    int n = (int)((t8 >> 8) & 4095);
    size_t si = (size_t)n * 2048 + (size_t)(t8 >> 20) * 256 + (t8 & 255);
    bfx8 a = *(const bfx8*)&sA[si];
    bfx8 bb = *(const bfx8*)&sB[si];
    float d = rsqrtf(dvr[n] + 1e-8f);
    f32x4 v0, v1;
#pragma unroll
    for (int t = 0; t < 4; t++) {
        v0[t] = d * ((float)a[t] + (float)bb[t]);
        v1[t] = d * ((float)a[4 + t] + (float)bb[4 + t]);
    }
    *(f32x4*)&out[t8] = v0;
    *(f32x4*)&out[t8 + 4] = v1;
}

// ---------------------------------------------------------------------------
extern "C" void kernel_launch(void* const* d_in, const int* in_sizes, int n_in,
                              void* d_out, int out_size, void* d_ws, size_t ws_size,
                              hipStream_t stream) {
    const float* x    = (const float*)d_in[0];
    const float* ew   = (const float*)d_in[1];
    const float* H    = (const float*)d_in[2];
    const float* W    = (const float*)d_in[3];
    const float* bias = (const float*)d_in[4];

    const int N = 4096, E = 2048;

    char* ws = (char*)d_ws;
    float* de   = (float*)(ws);
    float* dvr  = (float*)(ws + 8192);
    bf16*  HT   = (bf16*)(ws + 65536);                 // [E][N] 16 MB
    bf16*  xs_t = (bf16*)(ws + 65536 + 16777216);      // [2048][4096] 16 MB
    bf16*  t_t  = (bf16*)(ws + 65536 + 33554432);      // [2048][2048]  8 MB
    bf16*  wsHb = (bf16*)(ws + 65536 + 41943040);      // [N][E] 16 MB
    const bool bigws = ws_size >= 58785792ull + 4096ull;

    bf16* s0 = (bf16*)d_out;                           // K4 slice 0 (8 MB)
    bf16* s1 = s0 + 4194304;                           // K4 slice 1 (8 MB)

    (void)hipMemsetAsync(ws, 0, 24576, stream);  // de + dvr

    prep_kernel<<<dim3(E / 64, N / 64), 256, 0, stream>>>(
        H, ew, HT, bigws ? wsHb : nullptr, de, dvr, N, E);

    gemm_k3<<<dim3(64, 8), 256, 0, stream>>>(W, x, bias, dvr, xs_t);

    // K4 split-K=2, 256(c)x128(e) tiles, kLen=2048 (NT=32): slices in d_out
    gemm_tk<0><<<dim3(16, 8, 2), 512, 0, stream>>>(
        xs_t, HT, 4096, 32, s0, 2048, nullptr, nullptr);

    // t_t = bf16((s0+s1) * ew/(de+eps))
    combine2_kernel<<<dim3(2048), 256, 0, stream>>>(s0, s1, ew, de, t_t);

    if (bigws) {
        // K5 full-K 256x128, fused f32 epilogue -> final out (slices dead)
        gemm_tk<1><<<dim3(16, 16, 1), 512, 0, stream>>>(
            wsHb, t_t, 2048, 32, nullptr, 0, dvr, (float*)d_out);
    } else {
        // fallback: Hb via transpose into d_out, then 8-phase split-K K5
        bf16* HbP = (bf16*)d_out;
        transpose_kernel<<<dim3(64, 32), 256, 0, stream>>>(HT, HbP, 2048, 4096);
        bf16* k5a = HT;
        bf16* k5b = xs_t;
        gemm8ph<<<dim3(8, 16, 2), 512, 0, stream>>>(HbP, t_t, 2048, 1024, k5a, k5b, k5a, k5a, 2048);
        combine_out_kernel<<<dim3(4096), 256, 0, stream>>>(k5a, k5b, dvr, (float*)d_out);
    }
}